// Round 1
// baseline (2350.830 us; speedup 1.0000x reference)
//
#include <hip/hip_runtime.h>

// GlobalDistNet forward on MI355X. Round 1: fp32 correctness baseline.
// Pipeline: CSR build -> embed-gather GEMM -> input GCN -> 4x(GCN unit + GAT unit
// with GraphNorm + leaky-residual) -> scalar GCN -> fc1 -> fc2.

__device__ __forceinline__ float lrelu(float x, float s) { return x >= 0.f ? x : s * x; }

// ---------------- CSR build ----------------
__global__ __launch_bounds__(256) void k_deg(const int* __restrict__ dst,
                                             int* __restrict__ deg, int E) {
  int i = blockIdx.x * 256 + threadIdx.x;
  if (i < E) atomicAdd(&deg[dst[i]], 1);
}

__global__ __launch_bounds__(1024) void k_scan(const int* __restrict__ deg,
                                               int* __restrict__ row_ptr,
                                               float* __restrict__ dinv, int n) {
  __shared__ int sd[1024];
  __shared__ int sbase;
  int t = threadIdx.x;
  if (t == 0) { sbase = 0; row_ptr[0] = 0; }
  __syncthreads();
  for (int start = 0; start < n; start += 1024) {
    int i = start + t;
    int v = (i < n) ? deg[i] : 0;
    if (i < n) dinv[i] = rsqrtf((float)(v + 1));  // +1 self loop
    sd[t] = v;
    __syncthreads();
    for (int off = 1; off < 1024; off <<= 1) {
      int other = (t >= off) ? sd[t - off] : 0;
      __syncthreads();
      sd[t] += other;
      __syncthreads();
    }
    int base = sbase;
    if (i < n) row_ptr[i + 1] = base + sd[t];
    __syncthreads();
    if (t == 1023) sbase = base + sd[1023];
    __syncthreads();
  }
}

__global__ __launch_bounds__(256) void k_fill(const int* __restrict__ src,
                                              const int* __restrict__ dst,
                                              const int* __restrict__ row_ptr,
                                              int* __restrict__ fill,
                                              int* __restrict__ csr, int E) {
  int i = blockIdx.x * 256 + threadIdx.x;
  if (i < E) {
    int d = dst[i];
    int pos = row_ptr[d] + atomicAdd(&fill[d], 1);
    csr[pos] = src[i];
  }
}

// ---------------- GEMM tile compute (shared by both GEMMs) ----------------
// xs: [kk][node] (32x64), ws: [kk][chan] (32x128).
// Thread (cg,ng) computes nodes ng*4..+3, channels {cg*4..+3, 64+cg*4..+3}.
__device__ __forceinline__ void tile_mac(const float (*xs)[64], const float (*ws)[128],
                                         int cg, int ng, float acc[4][8]) {
#pragma unroll
  for (int kk = 0; kk < 32; kk++) {
    float4 xv = *(const float4*)&xs[kk][ng * 4];
    float4 wa = *(const float4*)&ws[kk][cg * 4];
    float4 wb = *(const float4*)&ws[kk][64 + cg * 4];
    float xq[4] = {xv.x, xv.y, xv.z, xv.w};
#pragma unroll
    for (int i = 0; i < 4; i++) {
      acc[i][0] += xq[i] * wa.x; acc[i][1] += xq[i] * wa.y;
      acc[i][2] += xq[i] * wa.z; acc[i][3] += xq[i] * wa.w;
      acc[i][4] += xq[i] * wb.x; acc[i][5] += xq[i] * wb.y;
      acc[i][6] += xq[i] * wb.z; acc[i][7] += xq[i] * wb.w;
    }
  }
}

__device__ __forceinline__ void tile_store(float* __restrict__ H, int bn, int cg, int ng,
                                           float acc[4][8], int n) {
#pragma unroll
  for (int i = 0; i < 4; i++) {
    int gn = bn + ng * 4 + i;
    if (gn < n) {
      float4 o0 = make_float4(acc[i][0], acc[i][1], acc[i][2], acc[i][3]);
      float4 o1 = make_float4(acc[i][4], acc[i][5], acc[i][6], acc[i][7]);
      *(float4*)(H + (size_t)gn * 128 + cg * 4) = o0;
      *(float4*)(H + (size_t)gn * 128 + 64 + cg * 4) = o1;
    }
  }
}

// h = x @ W for [N,128] x [128,128]
__global__ __launch_bounds__(256) void k_gemm128(const float* __restrict__ X,
                                                 const float* __restrict__ W,
                                                 float* __restrict__ H, int n) {
  __shared__ float xs[32][64];
  __shared__ float ws[32][128];
  int tid = threadIdx.x;
  int bn = blockIdx.x * 64;
  int cg = tid & 15, ng = tid >> 4;
  int ln = tid >> 2;           // load node 0..63
  int lk = (tid & 3) * 8;      // load k offset {0,8,16,24}
  int wk = tid >> 3;           // W row 0..31
  int wc = (tid & 7) * 16;     // W col
  int xrow = bn + ln; if (xrow > n - 1) xrow = n - 1;
  float acc[4][8];
#pragma unroll
  for (int i = 0; i < 4; i++)
#pragma unroll
    for (int j = 0; j < 8; j++) acc[i][j] = 0.f;

  for (int kc = 0; kc < 4; kc++) {
    const float4* xp = (const float4*)(X + (size_t)xrow * 128 + kc * 32 + lk);
    float4 a0 = xp[0], a1 = xp[1];
    const float4* wp = (const float4*)(W + (size_t)(kc * 32 + wk) * 128 + wc);
    float4 w0 = wp[0], w1 = wp[1], w2 = wp[2], w3 = wp[3];
    __syncthreads();
    xs[lk + 0][ln] = a0.x; xs[lk + 1][ln] = a0.y; xs[lk + 2][ln] = a0.z; xs[lk + 3][ln] = a0.w;
    xs[lk + 4][ln] = a1.x; xs[lk + 5][ln] = a1.y; xs[lk + 6][ln] = a1.z; xs[lk + 7][ln] = a1.w;
    *(float4*)&ws[wk][wc + 0] = w0; *(float4*)&ws[wk][wc + 4]  = w1;
    *(float4*)&ws[wk][wc + 8] = w2; *(float4*)&ws[wk][wc + 12] = w3;
    __syncthreads();
    tile_mac(xs, ws, cg, ng, acc);
  }
  tile_store(H, bn, cg, ng, acc, n);
}

// h = [emb(poi).flat || distance] @ W_in ; K = 4128 = 129 chunks of 32.
// chunk kc<128: poi slot j=kc/4, emb cols (kc%4)*32..+32 ; chunk 128: distance.
__global__ __launch_bounds__(256) void k_embed_gemm(const int* __restrict__ poi,
                                                    const float* __restrict__ dist,
                                                    const float* __restrict__ emb,
                                                    const float* __restrict__ W,
                                                    float* __restrict__ H, int n) {
  __shared__ float xs[32][64];
  __shared__ float ws[32][128];
  __shared__ int poi_s[64][32];
  int tid = threadIdx.x;
  int bn = blockIdx.x * 64;
  int cg = tid & 15, ng = tid >> 4;
  int ln = tid >> 2;
  int lk = (tid & 3) * 8;
  int wk = tid >> 3;
  int wc = (tid & 7) * 16;
  int xrow = bn + ln; if (xrow > n - 1) xrow = n - 1;

  { // stage poi indices for the 64 nodes
    int jb = (tid & 3) * 8;
    int4 p0 = *(const int4*)(poi + (size_t)xrow * 32 + jb);
    int4 p1 = *(const int4*)(poi + (size_t)xrow * 32 + jb + 4);
    *(int4*)&poi_s[ln][jb] = p0;
    *(int4*)&poi_s[ln][jb + 4] = p1;
  }
  __syncthreads();

  float acc[4][8];
#pragma unroll
  for (int i = 0; i < 4; i++)
#pragma unroll
    for (int j = 0; j < 8; j++) acc[i][j] = 0.f;

  for (int kc = 0; kc < 129; kc++) {
    float4 a0, a1;
    if (kc < 128) {
      int j = kc >> 2;
      int p = poi_s[ln][j];
      const float4* ep = (const float4*)(emb + (size_t)p * 128 + (kc & 3) * 32 + lk);
      a0 = ep[0]; a1 = ep[1];
    } else {
      const float4* dp = (const float4*)(dist + (size_t)xrow * 32 + lk);
      a0 = dp[0]; a1 = dp[1];
    }
    const float4* wp = (const float4*)(W + (size_t)(kc * 32 + wk) * 128 + wc);
    float4 w0 = wp[0], w1 = wp[1], w2 = wp[2], w3 = wp[3];
    __syncthreads();
    xs[lk + 0][ln] = a0.x; xs[lk + 1][ln] = a0.y; xs[lk + 2][ln] = a0.z; xs[lk + 3][ln] = a0.w;
    xs[lk + 4][ln] = a1.x; xs[lk + 5][ln] = a1.y; xs[lk + 6][ln] = a1.z; xs[lk + 7][ln] = a1.w;
    *(float4*)&ws[wk][wc + 0] = w0; *(float4*)&ws[wk][wc + 4]  = w1;
    *(float4*)&ws[wk][wc + 8] = w2; *(float4*)&ws[wk][wc + 12] = w3;
    __syncthreads();
    tile_mac(xs, ws, cg, ng, acc);
  }
  tile_store(H, bn, cg, ng, acc, n);
}

// ---------------- GCN aggregation (gather over CSR + self loop) ----------------
__global__ __launch_bounds__(128) void k_gcn_agg(const float* __restrict__ h,
                                                 const float* __restrict__ dinv,
                                                 const int* __restrict__ row_ptr,
                                                 const int* __restrict__ csr,
                                                 const float* __restrict__ bias,
                                                 float* __restrict__ out, int leaky_flag) {
  int node = blockIdx.x;
  int c = threadIdx.x;
  int rs = row_ptr[node], re = row_ptr[node + 1];
  float dn = dinv[node];
  float acc = dn * h[(size_t)node * 128 + c];  // self loop
  for (int i = rs; i < re; i++) {
    int s = csr[i];
    acc += dinv[s] * h[(size_t)s * 128 + c];
  }
  float v = dn * acc + bias[c];
  if (leaky_flag) v = lrelu(v, 0.01f);
  out[(size_t)node * 128 + c] = v;
}

// ---------------- GAT ----------------
__global__ __launch_bounds__(256) void k_dot2(const float* __restrict__ h,
                                              const float* __restrict__ a1,
                                              const float* __restrict__ a2,
                                              float* __restrict__ o1,
                                              float* __restrict__ o2, int n) {
  int node = blockIdx.x * 4 + (threadIdx.x >> 6);
  int lane = threadIdx.x & 63;
  if (node >= n) return;
  float2 hv = ((const float2*)h)[(size_t)node * 64 + lane];
  float2 v1 = ((const float2*)a1)[lane];
  float2 v2 = ((const float2*)a2)[lane];
  float s1 = hv.x * v1.x + hv.y * v1.y;
  float s2 = hv.x * v2.x + hv.y * v2.y;
  for (int off = 32; off > 0; off >>= 1) {
    s1 += __shfl_down(s1, off, 64);
    s2 += __shfl_down(s2, off, 64);
  }
  if (lane == 0) { o1[node] = s1; o2[node] = s2; }
}

__global__ __launch_bounds__(128) void k_gat_agg(const float* __restrict__ h,
                                                 const float* __restrict__ als,
                                                 const float* __restrict__ ald,
                                                 const int* __restrict__ row_ptr,
                                                 const int* __restrict__ csr,
                                                 const float* __restrict__ bias,
                                                 float* __restrict__ y) {
  int node = blockIdx.x;
  int c = threadIdx.x;  // 128
  __shared__ float red[128];
  int rs = row_ptr[node], re = row_ptr[node + 1];
  float aldn = ald[node];
  float e_self = lrelu(als[node] + aldn, 0.2f);
  // max logit
  float mx = e_self;
  for (int i = rs + c; i < re; i += 128)
    mx = fmaxf(mx, lrelu(als[csr[i]] + aldn, 0.2f));
  red[c] = mx; __syncthreads();
  for (int off = 64; off > 0; off >>= 1) {
    if (c < off) red[c] = fmaxf(red[c], red[c + off]);
    __syncthreads();
  }
  float m = red[0];
  __syncthreads();
  // softmax denominator
  float sm = (c == 0) ? __expf(e_self - m) : 0.f;
  for (int i = rs + c; i < re; i += 128)
    sm += __expf(lrelu(als[csr[i]] + aldn, 0.2f) - m);
  red[c] = sm; __syncthreads();
  for (int off = 64; off > 0; off >>= 1) {
    if (c < off) red[c] += red[c + off];
    __syncthreads();
  }
  float inv_s = 1.f / red[0];
  // weighted aggregation
  float acc = __expf(e_self - m) * h[(size_t)node * 128 + c];
  for (int i = rs; i < re; i++) {
    int s = csr[i];
    float wgt = __expf(lrelu(als[s] + aldn, 0.2f) - m);
    acc += wgt * h[(size_t)s * 128 + c];
  }
  y[(size_t)node * 128 + c] = acc * inv_s + bias[c];
}

// ---------------- GraphNorm (two-stage column stats, no atomics) ----------------
__global__ __launch_bounds__(256) void k_colstats(const float* __restrict__ y,
                                                  float* __restrict__ psum,
                                                  float* __restrict__ psumsq,
                                                  int n, int chunk) {
  int b = blockIdx.x, t = threadIdx.x;
  int c = t & 127, half = t >> 7;
  int s0 = b * chunk;
  int s1 = s0 + chunk; if (s1 > n) s1 = n;
  float s = 0.f, ss = 0.f;
  for (int i = s0 + half; i < s1; i += 2) {
    float v = y[(size_t)i * 128 + c];
    s += v; ss += v * v;
  }
  __shared__ float sh[256], sq[256];
  sh[t] = s; sq[t] = ss;
  __syncthreads();
  if (half == 0) {
    psum[b * 128 + c] = sh[c] + sh[c + 128];
    psumsq[b * 128 + c] = sq[c] + sq[c + 128];
  }
}

__global__ __launch_bounds__(128) void k_stats(const float* __restrict__ psum,
                                               const float* __restrict__ psumsq,
                                               const float* __restrict__ w,
                                               const float* __restrict__ bb,
                                               const float* __restrict__ ms,
                                               float* __restrict__ scaleA,
                                               float* __restrict__ shiftA, int n) {
  int c = threadIdx.x;
  double S = 0.0, SS = 0.0;
  for (int b = 0; b < 128; b++) { S += psum[b * 128 + c]; SS += psumsq[b * 128 + c]; }
  double invn = 1.0 / (double)n;
  double mean = S * invn;
  double mt = (double)ms[c] * mean;
  double var = SS * invn - 2.0 * mt * mean + mt * mt;
  float rstd = rsqrtf((float)var + 1e-5f);
  float sc = w[c] * rstd;
  scaleA[c] = sc;
  shiftA[c] = bb[c] - sc * (float)mt;
}

__global__ __launch_bounds__(256) void k_residual(const float* __restrict__ y,
                                                  const float* __restrict__ scaleA,
                                                  const float* __restrict__ shiftA,
                                                  float* __restrict__ x, int n4) {
  int i = blockIdx.x * 256 + threadIdx.x;
  if (i >= n4) return;
  int c4 = (i & 31) * 4;
  float4 yv = ((const float4*)y)[i];
  float4 xv = ((float4*)x)[i];
  float4 sc = *(const float4*)(scaleA + c4);
  float4 sh = *(const float4*)(shiftA + c4);
  xv.x += lrelu(sc.x * yv.x + sh.x, 0.01f);
  xv.y += lrelu(sc.y * yv.y + sh.y, 0.01f);
  xv.z += lrelu(sc.z * yv.z + sh.z, 0.01f);
  xv.w += lrelu(sc.w * yv.w + sh.w, 0.01f);
  ((float4*)x)[i] = xv;
}

// ---------------- Output head ----------------
__global__ __launch_bounds__(256) void k_dot1(const float* __restrict__ x,
                                              const float* __restrict__ wv,
                                              float* __restrict__ o, int n) {
  int node = blockIdx.x * 4 + (threadIdx.x >> 6);
  int lane = threadIdx.x & 63;
  if (node >= n) return;
  float2 hv = ((const float2*)x)[(size_t)node * 64 + lane];
  float2 v1 = ((const float2*)wv)[lane];
  float s1 = hv.x * v1.x + hv.y * v1.y;
  for (int off = 32; off > 0; off >>= 1) s1 += __shfl_down(s1, off, 64);
  if (lane == 0) o[node] = s1;
}

__global__ __launch_bounds__(256) void k_scalar_agg(const float* __restrict__ xsv,
                                                    const float* __restrict__ dinv,
                                                    const int* __restrict__ row_ptr,
                                                    const int* __restrict__ csr,
                                                    const float* __restrict__ b_out,
                                                    float* __restrict__ xout, int n) {
  int i = blockIdx.x * 256 + threadIdx.x;
  if (i >= n) return;
  float dn = dinv[i];
  float acc = dn * xsv[i];
  int re = row_ptr[i + 1];
  for (int e = row_ptr[i]; e < re; e++) {
    int s = csr[e];
    acc += dinv[s] * xsv[s];
  }
  xout[i] = lrelu(dn * acc + b_out[0], 0.01f);
}

__global__ __launch_bounds__(256) void k_fc1(const float* __restrict__ xout,
                                             const float* __restrict__ fw,
                                             float* __restrict__ pfc, int n, int chunk) {
  int b = blockIdx.x, t = threadIdx.x;
  int c = t & 127, half = t >> 7;
  int s0 = b * chunk;
  int s1 = s0 + chunk; if (s1 > n) s1 = n;
  float s = 0.f;
  for (int i = s0 + half; i < s1; i += 2) s += xout[i] * fw[(size_t)i * 128 + c];
  __shared__ float sh[256];
  sh[t] = s; __syncthreads();
  if (half == 0) pfc[b * 128 + c] = sh[c] + sh[c + 128];
}

__global__ __launch_bounds__(128) void k_final(const float* __restrict__ pfc,
                                               const float* __restrict__ b1,
                                               const float* __restrict__ fw2,
                                               const float* __restrict__ b2,
                                               float* __restrict__ out) {
  int c = threadIdx.x;
  float s = 0.f;
  for (int b = 0; b < 128; b++) s += pfc[b * 128 + c];
  float hv = lrelu(s + b1[c], 0.01f);
  __shared__ float h1[128];
  h1[c] = hv; __syncthreads();
  float o = b2[c];
  for (int j = 0; j < 128; j++) o += h1[j] * fw2[j * 128 + c];
  out[c] = o;
}

// ---------------- host ----------------
extern "C" void kernel_launch(void* const* d_in, const int* in_sizes, int n_in,
                              void* d_out, int out_size, void* d_ws, size_t ws_size,
                              hipStream_t stream) {
  const int* poi      = (const int*)d_in[0];
  const float* dist   = (const float*)d_in[1];
  const int* ei       = (const int*)d_in[2];
  const float* emb    = (const float*)d_in[3];
  const float* W_in   = (const float*)d_in[4];
  const float* b_in   = (const float*)d_in[5];
  const float* gcn_W  = (const float*)d_in[6];
  const float* gcn_b  = (const float*)d_in[7];
  const float* norm_w = (const float*)d_in[8];
  const float* norm_b = (const float*)d_in[9];
  const float* norm_ms= (const float*)d_in[10];
  const float* gat_W  = (const float*)d_in[11];
  const float* gat_as = (const float*)d_in[12];
  const float* gat_ad = (const float*)d_in[13];
  const float* gat_b  = (const float*)d_in[14];
  const float* W_out  = (const float*)d_in[15];
  const float* b_out  = (const float*)d_in[16];
  const float* fc1_W  = (const float*)d_in[17];
  const float* fc1_b  = (const float*)d_in[18];
  const float* fc2_W  = (const float*)d_in[19];
  const float* fc2_b  = (const float*)d_in[20];

  const int N = in_sizes[0] / 32;
  const int E = in_sizes[2] / 2;
  const int* srcp = ei;
  const int* dstp = ei + E;
  float* out = (float*)d_out;

  // workspace layout (floats, then ints; everything stays 16B aligned: N%4==0)
  float* w = (float*)d_ws;
  float* x    = w; w += (size_t)N * 128;
  float* h    = w; w += (size_t)N * 128;
  float* y    = w; w += (size_t)N * 128;
  float* dinv = w; w += N;
  float* als  = w; w += N;
  float* ald  = w; w += N;
  float* xsv  = w; w += N;
  float* xout = w; w += N;
  float* psum   = w; w += 128 * 128;
  float* psumsq = w; w += 128 * 128;
  float* pfc    = w; w += 128 * 128;
  float* scaleA = w; w += 128;
  float* shiftA = w; w += 128;
  int* deg     = (int*)w;
  int* fill    = deg + N;
  int* row_ptr = fill + N;
  int* csr     = row_ptr + (N + 1);

  const int chunk = (N + 127) / 128;        // nodes per column-stats block
  const int gblocks = (N + 63) / 64;        // GEMM node tiles
  const int eblocks = (E + 255) / 256;
  const int n4 = N * 32;                    // float4 count of [N,128]

  hipMemsetAsync(deg, 0, sizeof(int) * 2 * (size_t)N, stream);  // deg + fill
  k_deg<<<eblocks, 256, 0, stream>>>(dstp, deg, E);
  k_scan<<<1, 1024, 0, stream>>>(deg, row_ptr, dinv, N);
  k_fill<<<eblocks, 256, 0, stream>>>(srcp, dstp, row_ptr, fill, csr, E);

  // input layer: h = feat @ W_in ; x = leaky(gcn_agg(h) + b_in)
  k_embed_gemm<<<gblocks, 256, 0, stream>>>(poi, dist, emb, W_in, h, N);
  k_gcn_agg<<<N, 128, 0, stream>>>(h, dinv, row_ptr, csr, b_in, x, 1);

  for (int l = 0; l < 4; l++) {
    // GCN sub-unit
    k_gemm128<<<gblocks, 256, 0, stream>>>(x, gcn_W + (size_t)l * 16384, h, N);
    k_gcn_agg<<<N, 128, 0, stream>>>(h, dinv, row_ptr, csr, gcn_b + l * 128, y, 0);
    k_colstats<<<128, 256, 0, stream>>>(y, psum, psumsq, N, chunk);
    k_stats<<<1, 128, 0, stream>>>(psum, psumsq, norm_w + l * 128, norm_b + l * 128,
                                   norm_ms + l * 128, scaleA, shiftA, N);
    k_residual<<<(n4 + 255) / 256, 256, 0, stream>>>(y, scaleA, shiftA, x, n4);
    // GAT sub-unit
    k_gemm128<<<gblocks, 256, 0, stream>>>(x, gat_W + (size_t)l * 16384, h, N);
    k_dot2<<<(N + 3) / 4, 256, 0, stream>>>(h, gat_as + l * 128, gat_ad + l * 128, als, ald, N);
    k_gat_agg<<<N, 128, 0, stream>>>(h, als, ald, row_ptr, csr, gat_b + l * 128, y);
    k_colstats<<<128, 256, 0, stream>>>(y, psum, psumsq, N, chunk);
    k_stats<<<1, 128, 0, stream>>>(psum, psumsq, norm_w + l * 128, norm_b + l * 128,
                                   norm_ms + l * 128, scaleA, shiftA, N);
    k_residual<<<(n4 + 255) / 256, 256, 0, stream>>>(y, scaleA, shiftA, x, n4);
  }

  // output head
  k_dot1<<<(N + 3) / 4, 256, 0, stream>>>(x, W_out, xsv, N);
  k_scalar_agg<<<(N + 255) / 256, 256, 0, stream>>>(xsv, dinv, row_ptr, csr, b_out, xout, N);
  k_fc1<<<128, 256, 0, stream>>>(xout, fc1_W, pfc, N, chunk);
  k_final<<<1, 128, 0, stream>>>(pfc, fc1_b, fc2_W, fc2_b, out);
}

// Round 3
// 1690.578 us; speedup vs baseline: 1.3905x; 1.3905x over previous
//
#include <hip/hip_runtime.h>

// GlobalDistNet forward, round 3: split-bf16 MFMA GEMMs + wave-per-node aggregations.
// Round-2 crash fix: deg/fill must be ONE contiguous block (the 256B-aligned alloc
// padding made the combined memset miss the tail of `fill` -> poisoned atomic
// counters -> OOB csr writes -> device fault).

typedef short  s16x8 __attribute__((ext_vector_type(8)));
typedef unsigned short u16x8 __attribute__((ext_vector_type(8)));
typedef float  f32x4 __attribute__((ext_vector_type(4)));

__device__ __forceinline__ float lrelu(float x, float s){ return x>=0.f? x : s*x; }
__device__ __forceinline__ unsigned short f2bf(float f){
  unsigned u = __float_as_uint(f);
  u += 0x7fff + ((u>>16)&1);
  return (unsigned short)(u>>16);
}
__device__ __forceinline__ float bf2f(unsigned short h){ return __uint_as_float(((unsigned)h)<<16); }

// ---------------- CSR build ----------------
__global__ __launch_bounds__(256) void k_deg(const int* __restrict__ dst,
                                             int* __restrict__ deg, int E) {
  int i = blockIdx.x * 256 + threadIdx.x;
  if (i < E) atomicAdd(&deg[dst[i]], 1);
}

__global__ __launch_bounds__(1024) void k_scan(const int* __restrict__ deg,
                                               int* __restrict__ row_ptr,
                                               float* __restrict__ dinv, int n) {
  __shared__ int sd[1024];
  __shared__ int sbase;
  int t = threadIdx.x;
  if (t == 0) { sbase = 0; row_ptr[0] = 0; }
  __syncthreads();
  for (int start = 0; start < n; start += 1024) {
    int i = start + t;
    int v = (i < n) ? deg[i] : 0;
    if (i < n) dinv[i] = rsqrtf((float)(v + 1));  // +1 self loop
    sd[t] = v;
    __syncthreads();
    for (int off = 1; off < 1024; off <<= 1) {
      int other = (t >= off) ? sd[t - off] : 0;
      __syncthreads();
      sd[t] += other;
      __syncthreads();
    }
    int base = sbase;
    if (i < n) row_ptr[i + 1] = base + sd[t];
    __syncthreads();
    if (t == 1023) sbase = base + sd[1023];
    __syncthreads();
  }
}

__global__ __launch_bounds__(256) void k_fill(const int* __restrict__ src,
                                              const int* __restrict__ dst,
                                              const int* __restrict__ row_ptr,
                                              int* __restrict__ fill,
                                              int* __restrict__ csr, int E) {
  int i = blockIdx.x * 256 + threadIdx.x;
  if (i < E) {
    int d = dst[i];
    int pos = row_ptr[d] + atomicAdd(&fill[d], 1);
    csr[pos] = src[i];
  }
}

// ---------------- bf16 split / pack ----------------
__global__ __launch_bounds__(256) void k_split_emb(const float* __restrict__ src,
    unsigned short* __restrict__ hi, unsigned short* __restrict__ lo, int total4) {
  int i = blockIdx.x * 256 + threadIdx.x;
  if (i >= total4) return;
  float4 v = ((const float4*)src)[i];
  unsigned short h0=f2bf(v.x),h1=f2bf(v.y),h2=f2bf(v.z),h3=f2bf(v.w);
  unsigned short l0=f2bf(v.x-bf2f(h0)), l1=f2bf(v.y-bf2f(h1));
  unsigned short l2=f2bf(v.z-bf2f(h2)), l3=f2bf(v.w-bf2f(h3));
  uint2 hp, lp;
  hp.x = h0 | ((unsigned)h1<<16); hp.y = h2 | ((unsigned)h3<<16);
  lp.x = l0 | ((unsigned)l1<<16); lp.y = l2 | ((unsigned)l3<<16);
  ((uint2*)hi)[i] = hp; ((uint2*)lo)[i] = lp;
}

// W [K][128] fp32 -> Wp [K/8][128][8] bf16 hi/lo (MFMA B-fragment order)
__global__ __launch_bounds__(256) void k_pack_w(const float* __restrict__ W,
    unsigned short* __restrict__ hi, unsigned short* __restrict__ lo, int kb_total) {
  int idx = blockIdx.x * 256 + threadIdx.x;   // = kb*128 + c
  int c = idx & 127, kb = idx >> 7;
  if (kb >= kb_total) return;
  u16x8 hv, lv;
#pragma unroll
  for (int j = 0; j < 8; j++) {
    float v = W[(size_t)(kb*8 + j) * 128 + c];
    unsigned short h = f2bf(v);
    hv[j] = h; lv[j] = f2bf(v - bf2f(h));
  }
  ((u16x8*)hi)[idx] = hv;
  ((u16x8*)lo)[idx] = lv;
}

// 8 small 128x128 matrices (4 gcn + 4 gat) in one launch; grid (8, 8)
__global__ __launch_bounds__(256) void k_pack_w8(const float* __restrict__ gcnW,
    const float* __restrict__ gatW,
    unsigned short* __restrict__ hi, unsigned short* __restrict__ lo) {
  int mat = blockIdx.y;
  const float* W = (mat < 4) ? gcnW + (size_t)mat * 16384 : gatW + (size_t)(mat - 4) * 16384;
  int idx = blockIdx.x * 256 + threadIdx.x;   // 0..2047 = kb*128 + c
  int c = idx & 127, kb = idx >> 7;
  u16x8 hv, lv;
#pragma unroll
  for (int j = 0; j < 8; j++) {
    float v = W[(size_t)(kb*8 + j) * 128 + c];
    unsigned short h = f2bf(v);
    hv[j] = h; lv[j] = f2bf(v - bf2f(h));
  }
  ((u16x8*)hi)[mat * 2048 + idx] = hv;
  ((u16x8*)lo)[mat * 2048 + idx] = lv;
}

// ---------------- MFMA GEMM: embed-gather A, K=4128 ----------------
// Block: 64 nodes x 128 ch, 4 waves. Wave w: m-tiles {2(w&1),2(w&1)+1}, n-tiles 4(w>>1)..+3.
__global__ __launch_bounds__(256) void k_mfma_embed(const int* __restrict__ poi,
    const float* __restrict__ dist,
    const unsigned short* __restrict__ ehi, const unsigned short* __restrict__ elo,
    const unsigned short* __restrict__ whi, const unsigned short* __restrict__ wlo,
    float* __restrict__ H, int n) {
  __shared__ __attribute__((aligned(16))) unsigned short aH[64*32], aL[64*32];
  __shared__ __attribute__((aligned(16))) unsigned short bH[4*128*8], bL[4*128*8];
  __shared__ int poi_s[32*64];   // transposed [j][node] to avoid bank conflicts
  int tid = threadIdx.x;
  int bn = blockIdx.x * 64;
  int ln = tid >> 2, qt = tid & 3;
  int xrow = bn + ln; if (xrow > n - 1) xrow = n - 1;
  {
    int jb = qt * 8;
#pragma unroll
    for (int jj = 0; jj < 8; jj++) poi_s[(jb + jj) * 64 + ln] = poi[(size_t)xrow * 32 + jb + jj];
  }
  int w = tid >> 6, lane = tid & 63;
  int q = lane >> 4, l15 = lane & 15;
  int mtb = (w & 1) * 2;
  int ntb = (w >> 1) * 4;
  f32x4 acc[2][4];
#pragma unroll
  for (int a = 0; a < 2; a++)
#pragma unroll
    for (int b = 0; b < 4; b++) { acc[a][b][0]=0.f; acc[a][b][1]=0.f; acc[a][b][2]=0.f; acc[a][b][3]=0.f; }
  __syncthreads();

  for (int kc = 0; kc < 129; kc++) {
    u16x8 av_h, av_l;
    if (kc < 128) {
      int p = poi_s[(kc >> 2) * 64 + ln];
      size_t off = (size_t)p * 128 + (kc & 3) * 32 + qt * 8;
      av_h = *(const u16x8*)(ehi + off);
      av_l = *(const u16x8*)(elo + off);
    } else {
      const float* dp = dist + (size_t)xrow * 32 + qt * 8;
      float4 d0 = *(const float4*)dp, d1 = *(const float4*)(dp + 4);
      float dv[8] = {d0.x, d0.y, d0.z, d0.w, d1.x, d1.y, d1.z, d1.w};
#pragma unroll
      for (int j = 0; j < 8; j++) {
        unsigned short hh = f2bf(dv[j]);
        av_h[j] = hh; av_l[j] = f2bf(dv[j] - bf2f(hh));
      }
    }
    const u16x8* wp_h = (const u16x8*)(whi + (size_t)kc * 4096);
    const u16x8* wp_l = (const u16x8*)(wlo + (size_t)kc * 4096);
    u16x8 b0h = wp_h[tid], b1h = wp_h[tid + 256];
    u16x8 b0l = wp_l[tid], b1l = wp_l[tid + 256];
    __syncthreads();
    *(u16x8*)(aH + ln * 32 + qt * 8) = av_h;
    *(u16x8*)(aL + ln * 32 + qt * 8) = av_l;
    ((u16x8*)bH)[tid] = b0h; ((u16x8*)bH)[tid + 256] = b1h;
    ((u16x8*)bL)[tid] = b0l; ((u16x8*)bL)[tid + 256] = b1l;
    __syncthreads();
    s16x8 a_h[2], a_l[2];
#pragma unroll
    for (int mi = 0; mi < 2; mi++) {
      int off = ((mtb + mi) * 16 + l15) * 32 + q * 8;
      a_h[mi] = *(const s16x8*)(aH + off);
      a_l[mi] = *(const s16x8*)(aL + off);
    }
#pragma unroll
    for (int ni = 0; ni < 4; ni++) {
      int boff = (q * 128 + (ntb + ni) * 16 + l15) * 8;
      s16x8 b_h = *(const s16x8*)(bH + boff);
      s16x8 b_l = *(const s16x8*)(bL + boff);
#pragma unroll
      for (int mi = 0; mi < 2; mi++) {
        acc[mi][ni] = __builtin_amdgcn_mfma_f32_16x16x32_bf16(a_h[mi], b_h, acc[mi][ni], 0, 0, 0);
        acc[mi][ni] = __builtin_amdgcn_mfma_f32_16x16x32_bf16(a_l[mi], b_h, acc[mi][ni], 0, 0, 0);
        acc[mi][ni] = __builtin_amdgcn_mfma_f32_16x16x32_bf16(a_h[mi], b_l, acc[mi][ni], 0, 0, 0);
      }
    }
  }
#pragma unroll
  for (int mi = 0; mi < 2; mi++)
#pragma unroll
    for (int ni = 0; ni < 4; ni++)
#pragma unroll
      for (int r = 0; r < 4; r++) {
        int node = bn + (mtb + mi) * 16 + q * 4 + r;
        if (node < n) H[(size_t)node * 128 + (ntb + ni) * 16 + l15] = acc[mi][ni][r];
      }
}

// ---------------- MFMA GEMM: dense fp32 A (on-the-fly split), K=128 ----------------
__global__ __launch_bounds__(256) void k_mfma_lin(const float* __restrict__ X,
    const unsigned short* __restrict__ whi, const unsigned short* __restrict__ wlo,
    float* __restrict__ H, int n) {
  __shared__ __attribute__((aligned(16))) unsigned short aH[64*32], aL[64*32];
  __shared__ __attribute__((aligned(16))) unsigned short bH[4*128*8], bL[4*128*8];
  int tid = threadIdx.x;
  int bn = blockIdx.x * 64;
  int ln = tid >> 2, qt = tid & 3;
  int xrow = bn + ln; if (xrow > n - 1) xrow = n - 1;
  int w = tid >> 6, lane = tid & 63;
  int q = lane >> 4, l15 = lane & 15;
  int mtb = (w & 1) * 2;
  int ntb = (w >> 1) * 4;
  f32x4 acc[2][4];
#pragma unroll
  for (int a = 0; a < 2; a++)
#pragma unroll
    for (int b = 0; b < 4; b++) { acc[a][b][0]=0.f; acc[a][b][1]=0.f; acc[a][b][2]=0.f; acc[a][b][3]=0.f; }

  for (int kc = 0; kc < 4; kc++) {
    const float* xp = X + (size_t)xrow * 128 + kc * 32 + qt * 8;
    float4 x0 = *(const float4*)xp, x1 = *(const float4*)(xp + 4);
    float dv[8] = {x0.x, x0.y, x0.z, x0.w, x1.x, x1.y, x1.z, x1.w};
    u16x8 av_h, av_l;
#pragma unroll
    for (int j = 0; j < 8; j++) {
      unsigned short hh = f2bf(dv[j]);
      av_h[j] = hh; av_l[j] = f2bf(dv[j] - bf2f(hh));
    }
    const u16x8* wp_h = (const u16x8*)(whi + (size_t)kc * 4096);
    const u16x8* wp_l = (const u16x8*)(wlo + (size_t)kc * 4096);
    u16x8 b0h = wp_h[tid], b1h = wp_h[tid + 256];
    u16x8 b0l = wp_l[tid], b1l = wp_l[tid + 256];
    __syncthreads();
    *(u16x8*)(aH + ln * 32 + qt * 8) = av_h;
    *(u16x8*)(aL + ln * 32 + qt * 8) = av_l;
    ((u16x8*)bH)[tid] = b0h; ((u16x8*)bH)[tid + 256] = b1h;
    ((u16x8*)bL)[tid] = b0l; ((u16x8*)bL)[tid + 256] = b1l;
    __syncthreads();
    s16x8 a_h[2], a_l[2];
#pragma unroll
    for (int mi = 0; mi < 2; mi++) {
      int off = ((mtb + mi) * 16 + l15) * 32 + q * 8;
      a_h[mi] = *(const s16x8*)(aH + off);
      a_l[mi] = *(const s16x8*)(aL + off);
    }
#pragma unroll
    for (int ni = 0; ni < 4; ni++) {
      int boff = (q * 128 + (ntb + ni) * 16 + l15) * 8;
      s16x8 b_h = *(const s16x8*)(bH + boff);
      s16x8 b_l = *(const s16x8*)(bL + boff);
#pragma unroll
      for (int mi = 0; mi < 2; mi++) {
        acc[mi][ni] = __builtin_amdgcn_mfma_f32_16x16x32_bf16(a_h[mi], b_h, acc[mi][ni], 0, 0, 0);
        acc[mi][ni] = __builtin_amdgcn_mfma_f32_16x16x32_bf16(a_l[mi], b_h, acc[mi][ni], 0, 0, 0);
        acc[mi][ni] = __builtin_amdgcn_mfma_f32_16x16x32_bf16(a_h[mi], b_l, acc[mi][ni], 0, 0, 0);
      }
    }
  }
#pragma unroll
  for (int mi = 0; mi < 2; mi++)
#pragma unroll
    for (int ni = 0; ni < 4; ni++)
#pragma unroll
      for (int r = 0; r < 4; r++) {
        int node = bn + (mtb + mi) * 16 + q * 4 + r;
        if (node < n) H[(size_t)node * 128 + (ntb + ni) * 16 + l15] = acc[mi][ni][r];
      }
}

// ---------------- GCN aggregation: wave per node, float2 lanes ----------------
__global__ __launch_bounds__(256) void k_gcn_agg2(const float2* __restrict__ h2,
    const float* __restrict__ dinv, const int* __restrict__ row_ptr,
    const int* __restrict__ csr, const float* __restrict__ bias,
    float2* __restrict__ out2, int n, int leaky_flag) {
  int node = blockIdx.x * 4 + (threadIdx.x >> 6);
  int lane = threadIdx.x & 63;
  if (node >= n) return;
  int rs = row_ptr[node], re = row_ptr[node + 1];
  float dn = dinv[node];
  float2 self = h2[(size_t)node * 64 + lane];
  float ax = dn * self.x, ay = dn * self.y;
  int i = rs;
  for (; i + 1 < re; i += 2) {
    int s0 = csr[i], s1 = csr[i + 1];
    float w0 = dinv[s0], w1 = dinv[s1];
    float2 v0 = h2[(size_t)s0 * 64 + lane];
    float2 v1 = h2[(size_t)s1 * 64 + lane];
    ax += w0 * v0.x + w1 * v1.x;
    ay += w0 * v0.y + w1 * v1.y;
  }
  if (i < re) {
    int s = csr[i]; float wv = dinv[s];
    float2 v = h2[(size_t)s * 64 + lane];
    ax += wv * v.x; ay += wv * v.y;
  }
  float2 bv = ((const float2*)bias)[lane];
  float vx = dn * ax + bv.x, vy = dn * ay + bv.y;
  if (leaky_flag) { vx = lrelu(vx, 0.01f); vy = lrelu(vy, 0.01f); }
  out2[(size_t)node * 64 + lane] = make_float2(vx, vy);
}

// ---------------- GAT ----------------
__global__ __launch_bounds__(256) void k_dot2(const float* __restrict__ h,
                                              const float* __restrict__ a1,
                                              const float* __restrict__ a2,
                                              float* __restrict__ o1,
                                              float* __restrict__ o2, int n) {
  int node = blockIdx.x * 4 + (threadIdx.x >> 6);
  int lane = threadIdx.x & 63;
  if (node >= n) return;
  float2 hv = ((const float2*)h)[(size_t)node * 64 + lane];
  float2 v1 = ((const float2*)a1)[lane];
  float2 v2 = ((const float2*)a2)[lane];
  float s1 = hv.x * v1.x + hv.y * v1.y;
  float s2 = hv.x * v2.x + hv.y * v2.y;
  for (int off = 32; off > 0; off >>= 1) {
    s1 += __shfl_down(s1, off, 64);
    s2 += __shfl_down(s2, off, 64);
  }
  if (lane == 0) { o1[node] = s1; o2[node] = s2; }
}

__global__ __launch_bounds__(256) void k_gat_agg2(const float2* __restrict__ h2,
    const float* __restrict__ als, const float* __restrict__ ald,
    const int* __restrict__ row_ptr, const int* __restrict__ csr,
    const float* __restrict__ bias, float2* __restrict__ y2, int n) {
  int node = blockIdx.x * 4 + (threadIdx.x >> 6);
  int lane = threadIdx.x & 63;
  if (node >= n) return;
  int rs = row_ptr[node], re = row_ptr[node + 1];
  float aldn = ald[node];
  float e_self = lrelu(als[node] + aldn, 0.2f);
  float mx = e_self;
  for (int i = rs + lane; i < re; i += 64) mx = fmaxf(mx, lrelu(als[csr[i]] + aldn, 0.2f));
  for (int off = 1; off < 64; off <<= 1) mx = fmaxf(mx, __shfl_xor(mx, off, 64));
  float sm = 0.f;
  for (int i = rs + lane; i < re; i += 64) sm += __expf(lrelu(als[csr[i]] + aldn, 0.2f) - mx);
  for (int off = 1; off < 64; off <<= 1) sm += __shfl_xor(sm, off, 64);
  sm += __expf(e_self - mx);
  float inv_s = 1.f / sm;
  float2 self = h2[(size_t)node * 64 + lane];
  float wse = __expf(e_self - mx);
  float ax = wse * self.x, ay = wse * self.y;
  for (int i = rs; i < re; i++) {
    int s = csr[i];
    float wgt = __expf(lrelu(als[s] + aldn, 0.2f) - mx);
    float2 v = h2[(size_t)s * 64 + lane];
    ax += wgt * v.x; ay += wgt * v.y;
  }
  float2 bv = ((const float2*)bias)[lane];
  y2[(size_t)node * 64 + lane] = make_float2(ax * inv_s + bv.x, ay * inv_s + bv.y);
}

// ---------------- GraphNorm ----------------
__global__ __launch_bounds__(256) void k_colstats(const float* __restrict__ y,
                                                  float* __restrict__ psum,
                                                  float* __restrict__ psumsq,
                                                  int n, int chunk) {
  int b = blockIdx.x, t = threadIdx.x;
  int c = t & 127, half = t >> 7;
  int s0 = b * chunk;
  int s1 = s0 + chunk; if (s1 > n) s1 = n;
  float s = 0.f, ss = 0.f;
  for (int i = s0 + half; i < s1; i += 2) {
    float v = y[(size_t)i * 128 + c];
    s += v; ss += v * v;
  }
  __shared__ float sh[256], sq[256];
  sh[t] = s; sq[t] = ss;
  __syncthreads();
  if (half == 0) {
    psum[b * 128 + c] = sh[c] + sh[c + 128];
    psumsq[b * 128 + c] = sq[c] + sq[c + 128];
  }
}

__global__ __launch_bounds__(128) void k_stats(const float* __restrict__ psum,
                                               const float* __restrict__ psumsq,
                                               const float* __restrict__ w,
                                               const float* __restrict__ bb,
                                               const float* __restrict__ ms,
                                               float* __restrict__ scaleA,
                                               float* __restrict__ shiftA, int n) {
  int c = threadIdx.x;
  double S = 0.0, SS = 0.0;
  for (int b = 0; b < 128; b++) { S += psum[b * 128 + c]; SS += psumsq[b * 128 + c]; }
  double invn = 1.0 / (double)n;
  double mean = S * invn;
  double mt = (double)ms[c] * mean;
  double var = SS * invn - 2.0 * mt * mean + mt * mt;
  float rstd = rsqrtf((float)var + 1e-5f);
  float sc = w[c] * rstd;
  scaleA[c] = sc;
  shiftA[c] = bb[c] - sc * (float)mt;
}

__global__ __launch_bounds__(256) void k_residual(const float* __restrict__ y,
                                                  const float* __restrict__ scaleA,
                                                  const float* __restrict__ shiftA,
                                                  float* __restrict__ x, int n4) {
  int i = blockIdx.x * 256 + threadIdx.x;
  if (i >= n4) return;
  int c4 = (i & 31) * 4;
  float4 yv = ((const float4*)y)[i];
  float4 xv = ((float4*)x)[i];
  float4 sc = *(const float4*)(scaleA + c4);
  float4 sh = *(const float4*)(shiftA + c4);
  xv.x += lrelu(sc.x * yv.x + sh.x, 0.01f);
  xv.y += lrelu(sc.y * yv.y + sh.y, 0.01f);
  xv.z += lrelu(sc.z * yv.z + sh.z, 0.01f);
  xv.w += lrelu(sc.w * yv.w + sh.w, 0.01f);
  ((float4*)x)[i] = xv;
}

// ---------------- Output head ----------------
__global__ __launch_bounds__(256) void k_dot1(const float* __restrict__ x,
                                              const float* __restrict__ wv,
                                              float* __restrict__ o, int n) {
  int node = blockIdx.x * 4 + (threadIdx.x >> 6);
  int lane = threadIdx.x & 63;
  if (node >= n) return;
  float2 hv = ((const float2*)x)[(size_t)node * 64 + lane];
  float2 v1 = ((const float2*)wv)[lane];
  float s1 = hv.x * v1.x + hv.y * v1.y;
  for (int off = 32; off > 0; off >>= 1) s1 += __shfl_down(s1, off, 64);
  if (lane == 0) o[node] = s1;
}

__global__ __launch_bounds__(256) void k_scalar_agg(const float* __restrict__ xsv,
                                                    const float* __restrict__ dinv,
                                                    const int* __restrict__ row_ptr,
                                                    const int* __restrict__ csr,
                                                    const float* __restrict__ b_out,
                                                    float* __restrict__ xout, int n) {
  int i = blockIdx.x * 256 + threadIdx.x;
  if (i >= n) return;
  float dn = dinv[i];
  float acc = dn * xsv[i];
  int re = row_ptr[i + 1];
  for (int e = row_ptr[i]; e < re; e++) {
    int s = csr[e];
    acc += dinv[s] * xsv[s];
  }
  xout[i] = lrelu(dn * acc + b_out[0], 0.01f);
}

__global__ __launch_bounds__(256) void k_fc1(const float* __restrict__ xout,
                                             const float* __restrict__ fw,
                                             float* __restrict__ pfc, int n, int chunk) {
  int b = blockIdx.x, t = threadIdx.x;
  int c = t & 127, half = t >> 7;
  int s0 = b * chunk;
  int s1 = s0 + chunk; if (s1 > n) s1 = n;
  float s = 0.f;
  for (int i = s0 + half; i < s1; i += 2) s += xout[i] * fw[(size_t)i * 128 + c];
  __shared__ float sh[256];
  sh[t] = s; __syncthreads();
  if (half == 0) pfc[b * 128 + c] = sh[c] + sh[c + 128];
}

__global__ __launch_bounds__(128) void k_final(const float* __restrict__ pfc,
                                               const float* __restrict__ b1,
                                               const float* __restrict__ fw2,
                                               const float* __restrict__ b2,
                                               float* __restrict__ out) {
  int c = threadIdx.x;
  float s = 0.f;
  for (int b = 0; b < 128; b++) s += pfc[b * 128 + c];
  float hv = lrelu(s + b1[c], 0.01f);
  __shared__ float h1[128];
  h1[c] = hv; __syncthreads();
  float o = b2[c];
  for (int j = 0; j < 128; j++) o += h1[j] * fw2[j * 128 + c];
  out[c] = o;
}

// ---------------- host ----------------
extern "C" void kernel_launch(void* const* d_in, const int* in_sizes, int n_in,
                              void* d_out, int out_size, void* d_ws, size_t ws_size,
                              hipStream_t stream) {
  const int* poi      = (const int*)d_in[0];
  const float* dist   = (const float*)d_in[1];
  const int* ei       = (const int*)d_in[2];
  const float* emb    = (const float*)d_in[3];
  const float* W_in   = (const float*)d_in[4];
  const float* b_in   = (const float*)d_in[5];
  const float* gcn_W  = (const float*)d_in[6];
  const float* gcn_b  = (const float*)d_in[7];
  const float* norm_w = (const float*)d_in[8];
  const float* norm_b = (const float*)d_in[9];
  const float* norm_ms= (const float*)d_in[10];
  const float* gat_W  = (const float*)d_in[11];
  const float* gat_as = (const float*)d_in[12];
  const float* gat_ad = (const float*)d_in[13];
  const float* gat_b  = (const float*)d_in[14];
  const float* W_out  = (const float*)d_in[15];
  const float* b_out  = (const float*)d_in[16];
  const float* fc1_W  = (const float*)d_in[17];
  const float* fc1_b  = (const float*)d_in[18];
  const float* fc2_W  = (const float*)d_in[19];
  const float* fc2_b  = (const float*)d_in[20];

  const int N   = in_sizes[0] / 32;
  const int E   = in_sizes[2] / 2;
  const int POI = in_sizes[3] / 128;
  const int* srcp = ei;
  const int* dstp = ei + E;
  float* out = (float*)d_out;

  // workspace layout
  char* p = (char*)d_ws;
  auto alloc = [&](size_t bytes) { char* r = p; p += (bytes + 255) & ~(size_t)255; return r; };
  float* x = (float*)alloc((size_t)N * 128 * 4);
  float* h = (float*)alloc((size_t)N * 128 * 4);
  size_t Rneed = (size_t)POI * 128 * 2 * 2;          // emb hi+lo (bf16)
  size_t Ry = (size_t)N * 128 * 4;                   // y (fp32), reused after embed
  char* R = alloc(Rneed > Ry ? Rneed : Ry);
  unsigned short* ehi = (unsigned short*)R;
  unsigned short* elo = ehi + (size_t)POI * 128;
  float* y = (float*)R;
  const int KBIN = 4128 / 8;                          // 516
  unsigned short* wih = (unsigned short*)alloc((size_t)KBIN * 128 * 8 * 2);
  unsigned short* wil = (unsigned short*)alloc((size_t)KBIN * 128 * 8 * 2);
  unsigned short* wsh = (unsigned short*)alloc((size_t)8 * 16384 * 2);
  unsigned short* wsl = (unsigned short*)alloc((size_t)8 * 16384 * 2);
  float* dinv   = (float*)alloc((size_t)N * 4);
  float* als    = (float*)alloc((size_t)N * 4);
  float* ald    = (float*)alloc((size_t)N * 4);
  float* xsv    = (float*)alloc((size_t)N * 4);
  float* xout   = (float*)alloc((size_t)N * 4);
  float* psum   = (float*)alloc(128 * 128 * 4);
  float* psumsq = (float*)alloc(128 * 128 * 4);
  float* pfc    = (float*)alloc(128 * 128 * 4);
  float* scaleA = (float*)alloc(128 * 4);
  float* shiftA = (float*)alloc(128 * 4);
  // deg and fill MUST be one contiguous block: a single memset covers both.
  int* deg     = (int*)alloc((size_t)N * 2 * 4);
  int* fill    = deg + N;
  int* row_ptr = (int*)alloc(((size_t)N + 1) * 4);
  int* csr     = (int*)alloc((size_t)E * 4);

  const int chunk = (N + 127) / 128;
  const int gblocks = (N + 63) / 64;
  const int eblocks = (E + 255) / 256;
  const int n4 = N * 32;
  const int nwb = (N + 3) / 4;    // wave-per-node blocks

  hipMemsetAsync(deg, 0, sizeof(int) * 2 * (size_t)N, stream);
  k_deg<<<eblocks, 256, 0, stream>>>(dstp, deg, E);
  k_scan<<<1, 1024, 0, stream>>>(deg, row_ptr, dinv, N);
  k_fill<<<eblocks, 256, 0, stream>>>(srcp, dstp, row_ptr, fill, csr, E);

  // bf16 split / pack
  int et4 = POI * 128 / 4;
  k_split_emb<<<(et4 + 255) / 256, 256, 0, stream>>>(emb, ehi, elo, et4);
  k_pack_w<<<(KBIN * 128 + 255) / 256, 256, 0, stream>>>(W_in, wih, wil, KBIN);
  k_pack_w8<<<dim3(8, 8), 256, 0, stream>>>(gcn_W, gat_W, wsh, wsl);

  // input layer
  k_mfma_embed<<<gblocks, 256, 0, stream>>>(poi, dist, ehi, elo, wih, wil, h, N);
  k_gcn_agg2<<<nwb, 256, 0, stream>>>((const float2*)h, dinv, row_ptr, csr, b_in,
                                      (float2*)x, N, 1);

  for (int l = 0; l < 4; l++) {
    const unsigned short* gh = wsh + (size_t)l * 16384;
    const unsigned short* gl = wsl + (size_t)l * 16384;
    const unsigned short* th = wsh + (size_t)(4 + l) * 16384;
    const unsigned short* tl = wsl + (size_t)(4 + l) * 16384;
    // GCN sub-unit
    k_mfma_lin<<<gblocks, 256, 0, stream>>>(x, gh, gl, h, N);
    k_gcn_agg2<<<nwb, 256, 0, stream>>>((const float2*)h, dinv, row_ptr, csr,
                                        gcn_b + l * 128, (float2*)y, N, 0);
    k_colstats<<<128, 256, 0, stream>>>(y, psum, psumsq, N, chunk);
    k_stats<<<1, 128, 0, stream>>>(psum, psumsq, norm_w + l * 128, norm_b + l * 128,
                                   norm_ms + l * 128, scaleA, shiftA, N);
    k_residual<<<(n4 + 255) / 256, 256, 0, stream>>>(y, scaleA, shiftA, x, n4);
    // GAT sub-unit
    k_mfma_lin<<<gblocks, 256, 0, stream>>>(x, th, tl, h, N);
    k_dot2<<<nwb, 256, 0, stream>>>(h, gat_as + l * 128, gat_ad + l * 128, als, ald, N);
    k_gat_agg2<<<nwb, 256, 0, stream>>>((const float2*)h, als, ald, row_ptr, csr,
                                        gat_b + l * 128, (float2*)y, N);
    k_colstats<<<128, 256, 0, stream>>>(y, psum, psumsq, N, chunk);
    k_stats<<<1, 128, 0, stream>>>(psum, psumsq, norm_w + l * 128, norm_b + l * 128,
                                   norm_ms + l * 128, scaleA, shiftA, N);
    k_residual<<<(n4 + 255) / 256, 256, 0, stream>>>(y, scaleA, shiftA, x, n4);
  }

  // output head
  k_dot1<<<nwb, 256, 0, stream>>>(x, W_out, xsv, N);
  k_scalar_agg<<<(N + 255) / 256, 256, 0, stream>>>(xsv, dinv, row_ptr, csr, b_out, xout, N);
  k_fc1<<<128, 256, 0, stream>>>(xout, fc1_W, pfc, N, chunk);
  k_final<<<1, 128, 0, stream>>>(pfc, fc1_b, fc2_W, fc2_b, out);
}

// Round 4
// 1681.189 us; speedup vs baseline: 1.3983x; 1.0056x over previous
//
#include <hip/hip_runtime.h>

// GlobalDistNet forward, round 4:
//  - h stored as bf16 (halves aggregation gather bytes; error budget ~1e-3 final)
//  - LDS-free MFMA GEMMs: A/B fragments gathered directly from global in
//    fragment layout, no syncthreads in K-loop (round-3 showed the 2-barrier
//    K-loop left MfmaUtil at 25% with both pipes idle)
//  - GAT softmax: denominator fused into the weighted-aggregation pass

typedef short  s16x8 __attribute__((ext_vector_type(8)));
typedef unsigned short u16x8 __attribute__((ext_vector_type(8)));
typedef float  f32x4 __attribute__((ext_vector_type(4)));

__device__ __forceinline__ float lrelu(float x, float s){ return x>=0.f? x : s*x; }
__device__ __forceinline__ unsigned short f2bf(float f){
  unsigned u = __float_as_uint(f);
  u += 0x7fff + ((u>>16)&1);
  return (unsigned short)(u>>16);
}
__device__ __forceinline__ float bf2f(unsigned short h){ return __uint_as_float(((unsigned)h)<<16); }
__device__ __forceinline__ float bfu_lo(unsigned u){ return __uint_as_float(u<<16); }
__device__ __forceinline__ float bfu_hi(unsigned u){ return __uint_as_float(u & 0xffff0000u); }

// ---------------- CSR build ----------------
__global__ __launch_bounds__(256) void k_deg(const int* __restrict__ dst,
                                             int* __restrict__ deg, int E) {
  int i = blockIdx.x * 256 + threadIdx.x;
  if (i < E) atomicAdd(&deg[dst[i]], 1);
}

__global__ __launch_bounds__(1024) void k_scan(const int* __restrict__ deg,
                                               int* __restrict__ row_ptr,
                                               float* __restrict__ dinv, int n) {
  __shared__ int sd[1024];
  __shared__ int sbase;
  int t = threadIdx.x;
  if (t == 0) { sbase = 0; row_ptr[0] = 0; }
  __syncthreads();
  for (int start = 0; start < n; start += 1024) {
    int i = start + t;
    int v = (i < n) ? deg[i] : 0;
    if (i < n) dinv[i] = rsqrtf((float)(v + 1));  // +1 self loop
    sd[t] = v;
    __syncthreads();
    for (int off = 1; off < 1024; off <<= 1) {
      int other = (t >= off) ? sd[t - off] : 0;
      __syncthreads();
      sd[t] += other;
      __syncthreads();
    }
    int base = sbase;
    if (i < n) row_ptr[i + 1] = base + sd[t];
    __syncthreads();
    if (t == 1023) sbase = base + sd[1023];
    __syncthreads();
  }
}

__global__ __launch_bounds__(256) void k_fill(const int* __restrict__ src,
                                              const int* __restrict__ dst,
                                              const int* __restrict__ row_ptr,
                                              int* __restrict__ fill,
                                              int* __restrict__ csr, int E) {
  int i = blockIdx.x * 256 + threadIdx.x;
  if (i < E) {
    int d = dst[i];
    int pos = row_ptr[d] + atomicAdd(&fill[d], 1);
    csr[pos] = src[i];
  }
}

// ---------------- bf16 split / pack ----------------
__global__ __launch_bounds__(256) void k_split_emb(const float* __restrict__ src,
    unsigned short* __restrict__ hi, unsigned short* __restrict__ lo, int total4) {
  int i = blockIdx.x * 256 + threadIdx.x;
  if (i >= total4) return;
  float4 v = ((const float4*)src)[i];
  unsigned short h0=f2bf(v.x),h1=f2bf(v.y),h2=f2bf(v.z),h3=f2bf(v.w);
  unsigned short l0=f2bf(v.x-bf2f(h0)), l1=f2bf(v.y-bf2f(h1));
  unsigned short l2=f2bf(v.z-bf2f(h2)), l3=f2bf(v.w-bf2f(h3));
  uint2 hp, lp;
  hp.x = h0 | ((unsigned)h1<<16); hp.y = h2 | ((unsigned)h3<<16);
  lp.x = l0 | ((unsigned)l1<<16); lp.y = l2 | ((unsigned)l3<<16);
  ((uint2*)hi)[i] = hp; ((uint2*)lo)[i] = lp;
}

// W [K][128] fp32 -> Wp [K/8][128][8] bf16 hi/lo (MFMA B-fragment order)
__global__ __launch_bounds__(256) void k_pack_w(const float* __restrict__ W,
    unsigned short* __restrict__ hi, unsigned short* __restrict__ lo, int kb_total) {
  int idx = blockIdx.x * 256 + threadIdx.x;   // = kb*128 + c
  int c = idx & 127, kb = idx >> 7;
  if (kb >= kb_total) return;
  u16x8 hv, lv;
#pragma unroll
  for (int j = 0; j < 8; j++) {
    float v = W[(size_t)(kb*8 + j) * 128 + c];
    unsigned short h = f2bf(v);
    hv[j] = h; lv[j] = f2bf(v - bf2f(h));
  }
  ((u16x8*)hi)[idx] = hv;
  ((u16x8*)lo)[idx] = lv;
}

// 8 small 128x128 matrices (4 gcn + 4 gat); grid (8, 8)
__global__ __launch_bounds__(256) void k_pack_w8(const float* __restrict__ gcnW,
    const float* __restrict__ gatW,
    unsigned short* __restrict__ hi, unsigned short* __restrict__ lo) {
  int mat = blockIdx.y;
  const float* W = (mat < 4) ? gcnW + (size_t)mat * 16384 : gatW + (size_t)(mat - 4) * 16384;
  int idx = blockIdx.x * 256 + threadIdx.x;
  int c = idx & 127, kb = idx >> 7;
  u16x8 hv, lv;
#pragma unroll
  for (int j = 0; j < 8; j++) {
    float v = W[(size_t)(kb*8 + j) * 128 + c];
    unsigned short h = f2bf(v);
    hv[j] = h; lv[j] = f2bf(v - bf2f(h));
  }
  ((u16x8*)hi)[mat * 2048 + idx] = hv;
  ((u16x8*)lo)[mat * 2048 + idx] = lv;
}

// ---------------- MFMA GEMM: embed-gather A, K=4128, LDS-free K-loop ----------------
// Block: 64 nodes x 128 ch, 4 waves. Wave w: m-tiles {2(w&1),2(w&1)+1}, n-tiles 4(w>>1)..+3.
// A fragment: lane l needs A[m=l&15][k=(l>>4)*8+j] -> direct u16x8 gather from emb rows.
// B fragment: lane l needs B[k][n=16ni+(l&15)] -> direct u16x8 from packed [kb][c][8] W.
__global__ __launch_bounds__(256) void k_mfma_embed(const int* __restrict__ poi,
    const float* __restrict__ dist,
    const unsigned short* __restrict__ ehi, const unsigned short* __restrict__ elo,
    const unsigned short* __restrict__ whi, const unsigned short* __restrict__ wlo,
    unsigned short* __restrict__ H16, int n) {
  __shared__ int poi_s[32*64];                                      // [j][node]
  __shared__ __attribute__((aligned(16))) unsigned short ot[64*128]; // epilogue transpose
  int tid = threadIdx.x;
  int bn = blockIdx.x * 64;
  int ln = tid >> 2, qt = tid & 3;
  int xrow = bn + ln; if (xrow > n - 1) xrow = n - 1;
  {
    int jb = qt * 8;
#pragma unroll
    for (int jj = 0; jj < 8; jj++) poi_s[(jb + jj) * 64 + ln] = poi[(size_t)xrow * 32 + jb + jj];
  }
  int w = tid >> 6, lane = tid & 63;
  int q = lane >> 4, l15 = lane & 15;
  int mtb = (w & 1) * 2;
  int ntb = (w >> 1) * 4;
  int nc0 = bn + (mtb + 0) * 16 + l15; if (nc0 > n - 1) nc0 = n - 1;
  int nc1 = bn + (mtb + 1) * 16 + l15; if (nc1 > n - 1) nc1 = n - 1;
  f32x4 acc[2][4];
#pragma unroll
  for (int a = 0; a < 2; a++)
#pragma unroll
    for (int b = 0; b < 4; b++) { acc[a][b][0]=0.f; acc[a][b][1]=0.f; acc[a][b][2]=0.f; acc[a][b][3]=0.f; }
  __syncthreads();

#pragma unroll 1
  for (int kc = 0; kc < 129; kc++) {
    s16x8 a_h[2], a_l[2];
    if (kc < 128) {
      int jj = kc >> 2;
      int ko = (kc & 3) * 32 + q * 8;
      int p0 = poi_s[jj * 64 + (nc0 & 63)];
      int p1 = poi_s[jj * 64 + (nc1 & 63)];
      a_h[0] = *(const s16x8*)(ehi + (size_t)p0 * 128 + ko);
      a_l[0] = *(const s16x8*)(elo + (size_t)p0 * 128 + ko);
      a_h[1] = *(const s16x8*)(ehi + (size_t)p1 * 128 + ko);
      a_l[1] = *(const s16x8*)(elo + (size_t)p1 * 128 + ko);
    } else {
#pragma unroll
      for (int mi = 0; mi < 2; mi++) {
        int nc = mi ? nc1 : nc0;
        const float* dp = dist + (size_t)nc * 32 + q * 8;
        float4 d0 = *(const float4*)dp, d1 = *(const float4*)(dp + 4);
        float dv[8] = {d0.x, d0.y, d0.z, d0.w, d1.x, d1.y, d1.z, d1.w};
#pragma unroll
        for (int j = 0; j < 8; j++) {
          unsigned short hh = f2bf(dv[j]);
          a_h[mi][j] = (short)hh; a_l[mi][j] = (short)f2bf(dv[j] - bf2f(hh));
        }
      }
    }
#pragma unroll
    for (int ni = 0; ni < 4; ni++) {
      size_t boff = ((size_t)(kc * 4 + q) * 128 + (ntb + ni) * 16 + l15) * 8;
      s16x8 b_h = *(const s16x8*)(whi + boff);
      s16x8 b_l = *(const s16x8*)(wlo + boff);
#pragma unroll
      for (int mi = 0; mi < 2; mi++) {
        acc[mi][ni] = __builtin_amdgcn_mfma_f32_16x16x32_bf16(a_h[mi], b_h, acc[mi][ni], 0, 0, 0);
        acc[mi][ni] = __builtin_amdgcn_mfma_f32_16x16x32_bf16(a_l[mi], b_h, acc[mi][ni], 0, 0, 0);
        acc[mi][ni] = __builtin_amdgcn_mfma_f32_16x16x32_bf16(a_h[mi], b_l, acc[mi][ni], 0, 0, 0);
      }
    }
  }
  // epilogue: bf16 via LDS transpose, coalesced u16x8 stores
#pragma unroll
  for (int mi = 0; mi < 2; mi++)
#pragma unroll
    for (int ni = 0; ni < 4; ni++)
#pragma unroll
      for (int r = 0; r < 4; r++)
        ot[((mtb + mi) * 16 + q * 4 + r) * 128 + (ntb + ni) * 16 + l15] = f2bf(acc[mi][ni][r]);
  __syncthreads();
  if (bn + ln < n) {
    unsigned short* dst = H16 + (size_t)(bn + ln) * 128 + qt * 32;
    const unsigned short* srcp = ot + ln * 128 + qt * 32;
#pragma unroll
    for (int j = 0; j < 4; j++)
      *(u16x8*)(dst + j * 8) = *(const u16x8*)(srcp + j * 8);
  }
}

// ---------------- MFMA GEMM: dense fp32 A, K=128, LDS-free K-loop ----------------
__global__ __launch_bounds__(256) void k_mfma_lin(const float* __restrict__ X,
    const unsigned short* __restrict__ whi, const unsigned short* __restrict__ wlo,
    unsigned short* __restrict__ H16, int n) {
  __shared__ __attribute__((aligned(16))) unsigned short ot[64*128];
  int tid = threadIdx.x;
  int bn = blockIdx.x * 64;
  int ln = tid >> 2, qt = tid & 3;
  int w = tid >> 6, lane = tid & 63;
  int q = lane >> 4, l15 = lane & 15;
  int mtb = (w & 1) * 2;
  int ntb = (w >> 1) * 4;
  int nc0 = bn + (mtb + 0) * 16 + l15; if (nc0 > n - 1) nc0 = n - 1;
  int nc1 = bn + (mtb + 1) * 16 + l15; if (nc1 > n - 1) nc1 = n - 1;
  f32x4 acc[2][4];
#pragma unroll
  for (int a = 0; a < 2; a++)
#pragma unroll
    for (int b = 0; b < 4; b++) { acc[a][b][0]=0.f; acc[a][b][1]=0.f; acc[a][b][2]=0.f; acc[a][b][3]=0.f; }

#pragma unroll
  for (int kc = 0; kc < 4; kc++) {
    s16x8 a_h[2], a_l[2];
#pragma unroll
    for (int mi = 0; mi < 2; mi++) {
      int nc = mi ? nc1 : nc0;
      const float* xp = X + (size_t)nc * 128 + kc * 32 + q * 8;
      float4 x0 = *(const float4*)xp, x1 = *(const float4*)(xp + 4);
      float dv[8] = {x0.x, x0.y, x0.z, x0.w, x1.x, x1.y, x1.z, x1.w};
#pragma unroll
      for (int j = 0; j < 8; j++) {
        unsigned short hh = f2bf(dv[j]);
        a_h[mi][j] = (short)hh; a_l[mi][j] = (short)f2bf(dv[j] - bf2f(hh));
      }
    }
#pragma unroll
    for (int ni = 0; ni < 4; ni++) {
      size_t boff = ((size_t)(kc * 4 + q) * 128 + (ntb + ni) * 16 + l15) * 8;
      s16x8 b_h = *(const s16x8*)(whi + boff);
      s16x8 b_l = *(const s16x8*)(wlo + boff);
#pragma unroll
      for (int mi = 0; mi < 2; mi++) {
        acc[mi][ni] = __builtin_amdgcn_mfma_f32_16x16x32_bf16(a_h[mi], b_h, acc[mi][ni], 0, 0, 0);
        acc[mi][ni] = __builtin_amdgcn_mfma_f32_16x16x32_bf16(a_l[mi], b_h, acc[mi][ni], 0, 0, 0);
        acc[mi][ni] = __builtin_amdgcn_mfma_f32_16x16x32_bf16(a_h[mi], b_l, acc[mi][ni], 0, 0, 0);
      }
    }
  }
#pragma unroll
  for (int mi = 0; mi < 2; mi++)
#pragma unroll
    for (int ni = 0; ni < 4; ni++)
#pragma unroll
      for (int r = 0; r < 4; r++)
        ot[((mtb + mi) * 16 + q * 4 + r) * 128 + (ntb + ni) * 16 + l15] = f2bf(acc[mi][ni][r]);
  __syncthreads();
  if (bn + ln < n) {
    unsigned short* dst = H16 + (size_t)(bn + ln) * 128 + qt * 32;
    const unsigned short* srcp = ot + ln * 128 + qt * 32;
#pragma unroll
    for (int j = 0; j < 4; j++)
      *(u16x8*)(dst + j * 8) = *(const u16x8*)(srcp + j * 8);
  }
}

// ---------------- GCN aggregation: wave/node, bf16 rows (256 B) ----------------
__global__ __launch_bounds__(256) void k_gcn_agg16(const unsigned* __restrict__ h16,
    const float* __restrict__ dinv, const int* __restrict__ row_ptr,
    const int* __restrict__ csr, const float* __restrict__ bias,
    float2* __restrict__ out2, int n, int leaky_flag) {
  int node = blockIdx.x * 4 + (threadIdx.x >> 6);
  int lane = threadIdx.x & 63;
  if (node >= n) return;
  int rs = row_ptr[node], re = row_ptr[node + 1];
  float dn = dinv[node];
  unsigned su = h16[(size_t)node * 64 + lane];
  float ax = dn * bfu_lo(su), ay = dn * bfu_hi(su);
  int i = rs;
  for (; i + 1 < re; i += 2) {
    int s0 = csr[i], s1 = csr[i + 1];
    float w0 = dinv[s0], w1 = dinv[s1];
    unsigned u0 = h16[(size_t)s0 * 64 + lane];
    unsigned u1 = h16[(size_t)s1 * 64 + lane];
    ax += w0 * bfu_lo(u0) + w1 * bfu_lo(u1);
    ay += w0 * bfu_hi(u0) + w1 * bfu_hi(u1);
  }
  if (i < re) {
    int s = csr[i]; float wv = dinv[s];
    unsigned u = h16[(size_t)s * 64 + lane];
    ax += wv * bfu_lo(u); ay += wv * bfu_hi(u);
  }
  float2 bv = ((const float2*)bias)[lane];
  float vx = dn * ax + bv.x, vy = dn * ay + bv.y;
  if (leaky_flag) { vx = lrelu(vx, 0.01f); vy = lrelu(vy, 0.01f); }
  out2[(size_t)node * 64 + lane] = make_float2(vx, vy);
}

// ---------------- GAT ----------------
__global__ __launch_bounds__(256) void k_dot2_16(const unsigned* __restrict__ h16,
    const float* __restrict__ a1, const float* __restrict__ a2,
    float* __restrict__ o1, float* __restrict__ o2, int n) {
  int node = blockIdx.x * 4 + (threadIdx.x >> 6);
  int lane = threadIdx.x & 63;
  if (node >= n) return;
  unsigned u = h16[(size_t)node * 64 + lane];
  float hx = bfu_lo(u), hy = bfu_hi(u);
  float2 v1 = ((const float2*)a1)[lane];
  float2 v2 = ((const float2*)a2)[lane];
  float s1 = hx * v1.x + hy * v1.y;
  float s2 = hx * v2.x + hy * v2.y;
  for (int off = 32; off > 0; off >>= 1) {
    s1 += __shfl_down(s1, off, 64);
    s2 += __shfl_down(s2, off, 64);
  }
  if (lane == 0) { o1[node] = s1; o2[node] = s2; }
}

// softmax denominator fused into the weighted pass (accumulate unnormalized, scale once)
__global__ __launch_bounds__(256) void k_gat_agg16(const unsigned* __restrict__ h16,
    const float* __restrict__ als, const float* __restrict__ ald,
    const int* __restrict__ row_ptr, const int* __restrict__ csr,
    const float* __restrict__ bias, float2* __restrict__ y2, int n) {
  int node = blockIdx.x * 4 + (threadIdx.x >> 6);
  int lane = threadIdx.x & 63;
  if (node >= n) return;
  int rs = row_ptr[node], re = row_ptr[node + 1];
  float aldn = ald[node];
  float e_self = lrelu(als[node] + aldn, 0.2f);
  float mx = e_self;
  for (int i = rs + lane; i < re; i += 64) mx = fmaxf(mx, lrelu(als[csr[i]] + aldn, 0.2f));
  for (int off = 1; off < 64; off <<= 1) mx = fmaxf(mx, __shfl_xor(mx, off, 64));
  float ws = __expf(e_self - mx);
  float sm = ws;
  unsigned su = h16[(size_t)node * 64 + lane];
  float ax = ws * bfu_lo(su), ay = ws * bfu_hi(su);
  for (int i = rs; i < re; i++) {
    int s = csr[i];
    float wgt = __expf(lrelu(als[s] + aldn, 0.2f) - mx);
    sm += wgt;
    unsigned u = h16[(size_t)s * 64 + lane];
    ax += wgt * bfu_lo(u); ay += wgt * bfu_hi(u);
  }
  float inv_s = 1.f / sm;
  float2 bv = ((const float2*)bias)[lane];
  y2[(size_t)node * 64 + lane] = make_float2(ax * inv_s + bv.x, ay * inv_s + bv.y);
}

// ---------------- GraphNorm ----------------
__global__ __launch_bounds__(256) void k_colstats(const float* __restrict__ y,
                                                  float* __restrict__ psum,
                                                  float* __restrict__ psumsq,
                                                  int n, int chunk) {
  int b = blockIdx.x, t = threadIdx.x;
  int c = t & 127, half = t >> 7;
  int s0 = b * chunk;
  int s1 = s0 + chunk; if (s1 > n) s1 = n;
  float s = 0.f, ss = 0.f;
  for (int i = s0 + half; i < s1; i += 2) {
    float v = y[(size_t)i * 128 + c];
    s += v; ss += v * v;
  }
  __shared__ float sh[256], sq[256];
  sh[t] = s; sq[t] = ss;
  __syncthreads();
  if (half == 0) {
    psum[b * 128 + c] = sh[c] + sh[c + 128];
    psumsq[b * 128 + c] = sq[c] + sq[c + 128];
  }
}

__global__ __launch_bounds__(128) void k_stats(const float* __restrict__ psum,
                                               const float* __restrict__ psumsq,
                                               const float* __restrict__ w,
                                               const float* __restrict__ bb,
                                               const float* __restrict__ ms,
                                               float* __restrict__ scaleA,
                                               float* __restrict__ shiftA, int n) {
  int c = threadIdx.x;
  double S = 0.0, SS = 0.0;
  for (int b = 0; b < 128; b++) { S += psum[b * 128 + c]; SS += psumsq[b * 128 + c]; }
  double invn = 1.0 / (double)n;
  double mean = S * invn;
  double mt = (double)ms[c] * mean;
  double var = SS * invn - 2.0 * mt * mean + mt * mt;
  float rstd = rsqrtf((float)var + 1e-5f);
  float sc = w[c] * rstd;
  scaleA[c] = sc;
  shiftA[c] = bb[c] - sc * (float)mt;
}

__global__ __launch_bounds__(256) void k_residual(const float* __restrict__ y,
                                                  const float* __restrict__ scaleA,
                                                  const float* __restrict__ shiftA,
                                                  float* __restrict__ x, int n4) {
  int i = blockIdx.x * 256 + threadIdx.x;
  if (i >= n4) return;
  int c4 = (i & 31) * 4;
  float4 yv = ((const float4*)y)[i];
  float4 xv = ((float4*)x)[i];
  float4 sc = *(const float4*)(scaleA + c4);
  float4 sh = *(const float4*)(shiftA + c4);
  xv.x += lrelu(sc.x * yv.x + sh.x, 0.01f);
  xv.y += lrelu(sc.y * yv.y + sh.y, 0.01f);
  xv.z += lrelu(sc.z * yv.z + sh.z, 0.01f);
  xv.w += lrelu(sc.w * yv.w + sh.w, 0.01f);
  ((float4*)x)[i] = xv;
}

// ---------------- Output head ----------------
__global__ __launch_bounds__(256) void k_dot1(const float* __restrict__ x,
                                              const float* __restrict__ wv,
                                              float* __restrict__ o, int n) {
  int node = blockIdx.x * 4 + (threadIdx.x >> 6);
  int lane = threadIdx.x & 63;
  if (node >= n) return;
  float2 hv = ((const float2*)x)[(size_t)node * 64 + lane];
  float2 v1 = ((const float2*)wv)[lane];
  float s1 = hv.x * v1.x + hv.y * v1.y;
  for (int off = 32; off > 0; off >>= 1) s1 += __shfl_down(s1, off, 64);
  if (lane == 0) o[node] = s1;
}

__global__ __launch_bounds__(256) void k_scalar_agg(const float* __restrict__ xsv,
                                                    const float* __restrict__ dinv,
                                                    const int* __restrict__ row_ptr,
                                                    const int* __restrict__ csr,
                                                    const float* __restrict__ b_out,
                                                    float* __restrict__ xout, int n) {
  int i = blockIdx.x * 256 + threadIdx.x;
  if (i >= n) return;
  float dn = dinv[i];
  float acc = dn * xsv[i];
  int re = row_ptr[i + 1];
  for (int e = row_ptr[i]; e < re; e++) {
    int s = csr[e];
    acc += dinv[s] * xsv[s];
  }
  xout[i] = lrelu(dn * acc + b_out[0], 0.01f);
}

__global__ __launch_bounds__(256) void k_fc1(const float* __restrict__ xout,
                                             const float* __restrict__ fw,
                                             float* __restrict__ pfc, int n, int chunk) {
  int b = blockIdx.x, t = threadIdx.x;
  int c = t & 127, half = t >> 7;
  int s0 = b * chunk;
  int s1 = s0 + chunk; if (s1 > n) s1 = n;
  float s = 0.f;
  for (int i = s0 + half; i < s1; i += 2) s += xout[i] * fw[(size_t)i * 128 + c];
  __shared__ float sh[256];
  sh[t] = s; __syncthreads();
  if (half == 0) pfc[b * 128 + c] = sh[c] + sh[c + 128];
}

__global__ __launch_bounds__(128) void k_final(const float* __restrict__ pfc,
                                               const float* __restrict__ b1,
                                               const float* __restrict__ fw2,
                                               const float* __restrict__ b2,
                                               float* __restrict__ out) {
  int c = threadIdx.x;
  float s = 0.f;
  for (int b = 0; b < 128; b++) s += pfc[b * 128 + c];
  float hv = lrelu(s + b1[c], 0.01f);
  __shared__ float h1[128];
  h1[c] = hv; __syncthreads();
  float o = b2[c];
  for (int j = 0; j < 128; j++) o += h1[j] * fw2[j * 128 + c];
  out[c] = o;
}

// ---------------- host ----------------
extern "C" void kernel_launch(void* const* d_in, const int* in_sizes, int n_in,
                              void* d_out, int out_size, void* d_ws, size_t ws_size,
                              hipStream_t stream) {
  const int* poi      = (const int*)d_in[0];
  const float* dist   = (const float*)d_in[1];
  const int* ei       = (const int*)d_in[2];
  const float* emb    = (const float*)d_in[3];
  const float* W_in   = (const float*)d_in[4];
  const float* b_in   = (const float*)d_in[5];
  const float* gcn_W  = (const float*)d_in[6];
  const float* gcn_b  = (const float*)d_in[7];
  const float* norm_w = (const float*)d_in[8];
  const float* norm_b = (const float*)d_in[9];
  const float* norm_ms= (const float*)d_in[10];
  const float* gat_W  = (const float*)d_in[11];
  const float* gat_as = (const float*)d_in[12];
  const float* gat_ad = (const float*)d_in[13];
  const float* gat_b  = (const float*)d_in[14];
  const float* W_out  = (const float*)d_in[15];
  const float* b_out  = (const float*)d_in[16];
  const float* fc1_W  = (const float*)d_in[17];
  const float* fc1_b  = (const float*)d_in[18];
  const float* fc2_W  = (const float*)d_in[19];
  const float* fc2_b  = (const float*)d_in[20];

  const int N   = in_sizes[0] / 32;
  const int E   = in_sizes[2] / 2;
  const int POI = in_sizes[3] / 128;
  const int* srcp = ei;
  const int* dstp = ei + E;
  float* out = (float*)d_out;

  // workspace layout
  char* p = (char*)d_ws;
  auto alloc = [&](size_t bytes) { char* r = p; p += (bytes + 255) & ~(size_t)255; return r; };
  float* x = (float*)alloc((size_t)N * 128 * 4);
  unsigned short* h16 = (unsigned short*)alloc((size_t)N * 128 * 2);
  size_t Rneed = (size_t)POI * 128 * 2 * 2;          // emb hi+lo (bf16)
  size_t Ry = (size_t)N * 128 * 4;                   // y (fp32), reused after embed
  char* R = alloc(Rneed > Ry ? Rneed : Ry);
  unsigned short* ehi = (unsigned short*)R;
  unsigned short* elo = ehi + (size_t)POI * 128;
  float* y = (float*)R;
  const int KBIN = 4128 / 8;                          // 516
  unsigned short* wih = (unsigned short*)alloc((size_t)KBIN * 128 * 8 * 2);
  unsigned short* wil = (unsigned short*)alloc((size_t)KBIN * 128 * 8 * 2);
  unsigned short* wsh = (unsigned short*)alloc((size_t)8 * 16384 * 2);
  unsigned short* wsl = (unsigned short*)alloc((size_t)8 * 16384 * 2);
  float* dinv   = (float*)alloc((size_t)N * 4);
  float* als    = (float*)alloc((size_t)N * 4);
  float* ald    = (float*)alloc((size_t)N * 4);
  float* xsv    = (float*)alloc((size_t)N * 4);
  float* xout   = (float*)alloc((size_t)N * 4);
  float* psum   = (float*)alloc(128 * 128 * 4);
  float* psumsq = (float*)alloc(128 * 128 * 4);
  float* pfc    = (float*)alloc(128 * 128 * 4);
  float* scaleA = (float*)alloc(128 * 4);
  float* shiftA = (float*)alloc(128 * 4);
  // deg and fill MUST be one contiguous block: a single memset covers both.
  int* deg     = (int*)alloc((size_t)N * 2 * 4);
  int* fill    = deg + N;
  int* row_ptr = (int*)alloc(((size_t)N + 1) * 4);
  int* csr     = (int*)alloc((size_t)E * 4);

  const int chunk = (N + 127) / 128;
  const int gblocks = (N + 63) / 64;
  const int eblocks = (E + 255) / 256;
  const int n4 = N * 32;
  const int nwb = (N + 3) / 4;

  hipMemsetAsync(deg, 0, sizeof(int) * 2 * (size_t)N, stream);
  k_deg<<<eblocks, 256, 0, stream>>>(dstp, deg, E);
  k_scan<<<1, 1024, 0, stream>>>(deg, row_ptr, dinv, N);
  k_fill<<<eblocks, 256, 0, stream>>>(srcp, dstp, row_ptr, fill, csr, E);

  // bf16 split / pack
  int et4 = POI * 128 / 4;
  k_split_emb<<<(et4 + 255) / 256, 256, 0, stream>>>(emb, ehi, elo, et4);
  k_pack_w<<<(KBIN * 128 + 255) / 256, 256, 0, stream>>>(W_in, wih, wil, KBIN);
  k_pack_w8<<<dim3(8, 8), 256, 0, stream>>>(gcn_W, gat_W, wsh, wsl);

  // input layer
  k_mfma_embed<<<gblocks, 256, 0, stream>>>(poi, dist, ehi, elo, wih, wil, h16, N);
  k_gcn_agg16<<<nwb, 256, 0, stream>>>((const unsigned*)h16, dinv, row_ptr, csr, b_in,
                                       (float2*)x, N, 1);

  for (int l = 0; l < 4; l++) {
    const unsigned short* gh = wsh + (size_t)l * 16384;
    const unsigned short* gl = wsl + (size_t)l * 16384;
    const unsigned short* th = wsh + (size_t)(4 + l) * 16384;
    const unsigned short* tl = wsl + (size_t)(4 + l) * 16384;
    // GCN sub-unit
    k_mfma_lin<<<gblocks, 256, 0, stream>>>(x, gh, gl, h16, N);
    k_gcn_agg16<<<nwb, 256, 0, stream>>>((const unsigned*)h16, dinv, row_ptr, csr,
                                         gcn_b + l * 128, (float2*)y, N, 0);
    k_colstats<<<128, 256, 0, stream>>>(y, psum, psumsq, N, chunk);
    k_stats<<<1, 128, 0, stream>>>(psum, psumsq, norm_w + l * 128, norm_b + l * 128,
                                   norm_ms + l * 128, scaleA, shiftA, N);
    k_residual<<<(n4 + 255) / 256, 256, 0, stream>>>(y, scaleA, shiftA, x, n4);
    // GAT sub-unit
    k_mfma_lin<<<gblocks, 256, 0, stream>>>(x, th, tl, h16, N);
    k_dot2_16<<<nwb, 256, 0, stream>>>((const unsigned*)h16, gat_as + l * 128,
                                       gat_ad + l * 128, als, ald, N);
    k_gat_agg16<<<nwb, 256, 0, stream>>>((const unsigned*)h16, als, ald, row_ptr, csr,
                                         gat_b + l * 128, (float2*)y, N);
    k_colstats<<<128, 256, 0, stream>>>(y, psum, psumsq, N, chunk);
    k_stats<<<1, 128, 0, stream>>>(psum, psumsq, norm_w + l * 128, norm_b + l * 128,
                                   norm_ms + l * 128, scaleA, shiftA, N);
    k_residual<<<(n4 + 255) / 256, 256, 0, stream>>>(y, scaleA, shiftA, x, n4);
  }

  // output head
  k_dot1<<<nwb, 256, 0, stream>>>(x, W_out, xsv, N);
  k_scalar_agg<<<(N + 255) / 256, 256, 0, stream>>>(xsv, dinv, row_ptr, csr, b_out, xout, N);
  k_fc1<<<128, 256, 0, stream>>>(xout, fc1_W, pfc, N, chunk);
  k_final<<<1, 128, 0, stream>>>(pfc, fc1_b, fc2_W, fc2_b, out);
}

// Round 5
// 1577.737 us; speedup vs baseline: 1.4900x; 1.0656x over previous
//
#include <hip/hip_runtime.h>

// GlobalDistNet forward, round 5: f16 pipeline.
//  - emb table converted to ONE f16 copy (halves gather bytes vs hi+lo); W f16 hi/lo
//  - embed GEMM: full-row LDS staging per poi slot, reg-prefetch, 64 MFMA/barrier-pair
//  - h stored f16 (better accuracy than bf16 AND same bytes)
//  - fusions: dot2 -> lin epilogue; k_stats -> colstats last-block; residual emits xh
//  - agg edge loops unrolled for memory ILP

typedef _Float16 f16;
typedef f16 f16x8 __attribute__((ext_vector_type(8)));
typedef f16 f16x4 __attribute__((ext_vector_type(4)));
typedef f16 f16x2 __attribute__((ext_vector_type(2)));
typedef float f32x4 __attribute__((ext_vector_type(4)));

__device__ __forceinline__ float lrelu(float x, float s){ return x>=0.f? x : s*x; }

// ---------------- CSR build ----------------
__global__ __launch_bounds__(256) void k_deg(const int* __restrict__ dst,
                                             int* __restrict__ deg, int E) {
  int i = blockIdx.x * 256 + threadIdx.x;
  if (i < E) atomicAdd(&deg[dst[i]], 1);
}

__global__ __launch_bounds__(1024) void k_scan(const int* __restrict__ deg,
                                               int* __restrict__ row_ptr,
                                               float* __restrict__ dinv, int n) {
  __shared__ int sd[1024];
  __shared__ int sbase;
  int t = threadIdx.x;
  if (t == 0) { sbase = 0; row_ptr[0] = 0; }
  __syncthreads();
  for (int start = 0; start < n; start += 1024) {
    int i = start + t;
    int v = (i < n) ? deg[i] : 0;
    if (i < n) dinv[i] = rsqrtf((float)(v + 1));
    sd[t] = v;
    __syncthreads();
    for (int off = 1; off < 1024; off <<= 1) {
      int other = (t >= off) ? sd[t - off] : 0;
      __syncthreads();
      sd[t] += other;
      __syncthreads();
    }
    int base = sbase;
    if (i < n) row_ptr[i + 1] = base + sd[t];
    __syncthreads();
    if (t == 1023) sbase = base + sd[1023];
    __syncthreads();
  }
}

__global__ __launch_bounds__(256) void k_fill(const int* __restrict__ src,
                                              const int* __restrict__ dst,
                                              const int* __restrict__ row_ptr,
                                              int* __restrict__ fill,
                                              int* __restrict__ csr, int E) {
  int i = blockIdx.x * 256 + threadIdx.x;
  if (i < E) {
    int d = dst[i];
    int pos = row_ptr[d] + atomicAdd(&fill[d], 1);
    csr[pos] = src[i];
  }
}

// ---------------- conversions / packing ----------------
__global__ __launch_bounds__(256) void k_conv_emb(const float* __restrict__ src,
                                                  f16* __restrict__ dst, int total4) {
  int i = blockIdx.x * 256 + threadIdx.x;
  if (i >= total4) return;
  float4 v = ((const float4*)src)[i];
  f16x4 o = { (f16)v.x, (f16)v.y, (f16)v.z, (f16)v.w };
  ((f16x4*)dst)[i] = o;
}

// W [K][128] fp32 -> [K/8][128][8] f16 hi/lo (MFMA B-fragment order)
__global__ __launch_bounds__(256) void k_pack_w(const float* __restrict__ W,
    f16* __restrict__ hi, f16* __restrict__ lo, int kb_total) {
  int idx = blockIdx.x * 256 + threadIdx.x;
  int c = idx & 127, kb = idx >> 7;
  if (kb >= kb_total) return;
  f16x8 hv, lv;
#pragma unroll
  for (int j = 0; j < 8; j++) {
    float v = W[(size_t)(kb*8 + j) * 128 + c];
    f16 h = (f16)v;
    hv[j] = h; lv[j] = (f16)(v - (float)h);
  }
  ((f16x8*)hi)[idx] = hv;
  ((f16x8*)lo)[idx] = lv;
}

__global__ __launch_bounds__(256) void k_pack_w8(const float* __restrict__ gcnW,
    const float* __restrict__ gatW, f16* __restrict__ hi, f16* __restrict__ lo) {
  int mat = blockIdx.y;
  const float* W = (mat < 4) ? gcnW + (size_t)mat * 16384 : gatW + (size_t)(mat - 4) * 16384;
  int idx = blockIdx.x * 256 + threadIdx.x;
  int c = idx & 127, kb = idx >> 7;
  f16x8 hv, lv;
#pragma unroll
  for (int j = 0; j < 8; j++) {
    float v = W[(size_t)(kb*8 + j) * 128 + c];
    f16 h = (f16)v;
    hv[j] = h; lv[j] = (f16)(v - (float)h);
  }
  ((f16x8*)hi)[mat * 2048 + idx] = hv;
  ((f16x8*)lo)[mat * 2048 + idx] = lv;
}

// ---------------- MFMA GEMM: embed-gather A, K=4128 ----------------
// 64 nodes x 128 ch per block, 4 waves. Per poi-slot j: stage full 256-B f16 rows
// into LDS (coalesced), reg-prefetch next j, then 4 kc iters (64 MFMAs/wave).
#define APAD 152   // row stride in halves: 304 B, 16B-aligned, 2-way-conflict reads
__global__ __launch_bounds__(256) void k_mfma_embed(const int* __restrict__ poi,
    const float* __restrict__ dist, const f16* __restrict__ eh,
    const f16* __restrict__ wh, const f16* __restrict__ wl,
    f16* __restrict__ H16, int n) {
  __shared__ __attribute__((aligned(16))) char smem[8192 + 64 * APAD * 2];
  int* poi_s = (int*)smem;                // [32][64]
  f16* aS = (f16*)(smem + 8192);          // [64][APAD]
  f16* ot = (f16*)(smem + 8192);          // alias (epilogue)
  int tid = threadIdx.x;
  int bn = blockIdx.x * 64;
  int ln = tid >> 2, qt = tid & 3;
  int xrow = bn + ln; if (xrow > n - 1) xrow = n - 1;
  {
    int jb = qt * 8;
#pragma unroll
    for (int jj = 0; jj < 8; jj++) poi_s[(jb + jj) * 64 + ln] = poi[(size_t)xrow * 32 + jb + jj];
  }
  int w = tid >> 6, lane = tid & 63;
  int q = lane >> 4, l15 = lane & 15;
  int mtb = (w & 1) * 2;
  int ntb = (w >> 1) * 4;
  f32x4 acc[2][4];
#pragma unroll
  for (int a = 0; a < 2; a++)
#pragma unroll
    for (int b = 0; b < 4; b++) { acc[a][b][0]=0.f; acc[a][b][1]=0.f; acc[a][b][2]=0.f; acc[a][b][3]=0.f; }
  __syncthreads();   // poi_s ready

  // prefetch j=0 row slice (thread covers bytes [qt*64, qt*64+64) of its row)
  f16x8 r0, r1, r2, r3;
  {
    const f16* srcp = eh + (size_t)poi_s[ln] * 128 + qt * 32;
    r0 = *(const f16x8*)(srcp);     r1 = *(const f16x8*)(srcp + 8);
    r2 = *(const f16x8*)(srcp + 16); r3 = *(const f16x8*)(srcp + 24);
  }

#pragma unroll 1
  for (int j = 0; j < 32; j++) {
    __syncthreads();   // previous j's reads done
    f16* wp = aS + ln * APAD + qt * 32;
    *(f16x8*)(wp) = r0; *(f16x8*)(wp + 8) = r1;
    *(f16x8*)(wp + 16) = r2; *(f16x8*)(wp + 24) = r3;
    if (j + 1 < 32) {
      const f16* srcp = eh + (size_t)poi_s[(j + 1) * 64 + ln] * 128 + qt * 32;
      r0 = *(const f16x8*)(srcp);     r1 = *(const f16x8*)(srcp + 8);
      r2 = *(const f16x8*)(srcp + 16); r3 = *(const f16x8*)(srcp + 24);
    }
    __syncthreads();   // aS ready
#pragma unroll
    for (int kcl = 0; kcl < 4; kcl++) {
      f16x8 a_h[2];
#pragma unroll
      for (int mi = 0; mi < 2; mi++)
        a_h[mi] = *(const f16x8*)(aS + ((mtb + mi) * 16 + l15) * APAD + kcl * 32 + q * 8);
      int kb = j * 16 + kcl * 4 + q;
#pragma unroll
      for (int ni = 0; ni < 4; ni++) {
        size_t boff = ((size_t)kb * 128 + (ntb + ni) * 16 + l15) * 8;
        f16x8 bh = *(const f16x8*)(wh + boff);
        f16x8 bl = *(const f16x8*)(wl + boff);
#pragma unroll
        for (int mi = 0; mi < 2; mi++) {
          acc[mi][ni] = __builtin_amdgcn_mfma_f32_16x16x32_f16(a_h[mi], bh, acc[mi][ni], 0, 0, 0);
          acc[mi][ni] = __builtin_amdgcn_mfma_f32_16x16x32_f16(a_h[mi], bl, acc[mi][ni], 0, 0, 0);
        }
      }
    }
  }
  // distance chunk: k = 4096..4127
  {
    int nc0 = bn + (mtb + 0) * 16 + l15; if (nc0 > n - 1) nc0 = n - 1;
    int nc1 = bn + (mtb + 1) * 16 + l15; if (nc1 > n - 1) nc1 = n - 1;
    f16x8 ad[2];
#pragma unroll
    for (int mi = 0; mi < 2; mi++) {
      int nc = mi ? nc1 : nc0;
      const float* dp = dist + (size_t)nc * 32 + q * 8;
      float4 d0 = *(const float4*)dp, d1 = *(const float4*)(dp + 4);
      ad[mi][0]=(f16)d0.x; ad[mi][1]=(f16)d0.y; ad[mi][2]=(f16)d0.z; ad[mi][3]=(f16)d0.w;
      ad[mi][4]=(f16)d1.x; ad[mi][5]=(f16)d1.y; ad[mi][6]=(f16)d1.z; ad[mi][7]=(f16)d1.w;
    }
    int kb = 512 + q;
#pragma unroll
    for (int ni = 0; ni < 4; ni++) {
      size_t boff = ((size_t)kb * 128 + (ntb + ni) * 16 + l15) * 8;
      f16x8 bh = *(const f16x8*)(wh + boff);
      f16x8 bl = *(const f16x8*)(wl + boff);
#pragma unroll
      for (int mi = 0; mi < 2; mi++) {
        acc[mi][ni] = __builtin_amdgcn_mfma_f32_16x16x32_f16(ad[mi], bh, acc[mi][ni], 0, 0, 0);
        acc[mi][ni] = __builtin_amdgcn_mfma_f32_16x16x32_f16(ad[mi], bl, acc[mi][ni], 0, 0, 0);
      }
    }
  }
  __syncthreads();   // aS dead; ot alias safe
#pragma unroll
  for (int mi = 0; mi < 2; mi++)
#pragma unroll
    for (int ni = 0; ni < 4; ni++)
#pragma unroll
      for (int r = 0; r < 4; r++)
        ot[((mtb + mi) * 16 + q * 4 + r) * 128 + (ntb + ni) * 16 + l15] = (f16)acc[mi][ni][r];
  __syncthreads();
  if (bn + ln < n) {
    f16* dst = H16 + (size_t)(bn + ln) * 128 + qt * 32;
    const f16* srcp = ot + ln * 128 + qt * 32;
#pragma unroll
    for (int jj = 0; jj < 4; jj++)
      *(f16x8*)(dst + jj * 8) = *(const f16x8*)(srcp + jj * 8);
  }
}

// ---------------- MFMA GEMM: f16 A (xh), K=128; optional fused a-dot epilogue ----
#define LPAD 136   // 272 B rows, 16B-aligned, 2-way reads
__global__ __launch_bounds__(256) void k_mfma_lin(const f16* __restrict__ XH,
    const f16* __restrict__ wh, const f16* __restrict__ wl,
    f16* __restrict__ H16, int n,
    const float* __restrict__ asrc, const float* __restrict__ adst,
    float* __restrict__ als, float* __restrict__ ald) {
  __shared__ __attribute__((aligned(16))) char smem[64 * LPAD * 2];   // 17408 B
  f16* aS = (f16*)smem;                  // [64][LPAD]
  f16* ot = (f16*)smem;                  // [64][128] alias
  float* dsrc = (float*)(smem + 16384);  // [64][2]
  float* ddst = (float*)(smem + 16896);  // [64][2] (16896+512 = 17408)
  int tid = threadIdx.x;
  int bn = blockIdx.x * 64;
  int ln = tid >> 2, qt = tid & 3;
  int xrow = bn + ln; if (xrow > n - 1) xrow = n - 1;
  int w = tid >> 6, lane = tid & 63;
  int q = lane >> 4, l15 = lane & 15;
  int mtb = (w & 1) * 2;
  int ntb = (w >> 1) * 4;
  {
    const f16* srcp = XH + (size_t)xrow * 128 + qt * 32;
    f16* wp = aS + ln * LPAD + qt * 32;
    *(f16x8*)(wp)      = *(const f16x8*)(srcp);
    *(f16x8*)(wp + 8)  = *(const f16x8*)(srcp + 8);
    *(f16x8*)(wp + 16) = *(const f16x8*)(srcp + 16);
    *(f16x8*)(wp + 24) = *(const f16x8*)(srcp + 24);
  }
  float av[4], bv[4];
  if (asrc) {
#pragma unroll
    for (int ni = 0; ni < 4; ni++) {
      av[ni] = asrc[(ntb + ni) * 16 + l15];
      bv[ni] = adst[(ntb + ni) * 16 + l15];
    }
  }
  f32x4 acc[2][4];
#pragma unroll
  for (int a = 0; a < 2; a++)
#pragma unroll
    for (int b = 0; b < 4; b++) { acc[a][b][0]=0.f; acc[a][b][1]=0.f; acc[a][b][2]=0.f; acc[a][b][3]=0.f; }
  __syncthreads();
#pragma unroll
  for (int kcl = 0; kcl < 4; kcl++) {
    f16x8 a_h[2];
#pragma unroll
    for (int mi = 0; mi < 2; mi++)
      a_h[mi] = *(const f16x8*)(aS + ((mtb + mi) * 16 + l15) * LPAD + kcl * 32 + q * 8);
    int kb = kcl * 4 + q;
#pragma unroll
    for (int ni = 0; ni < 4; ni++) {
      size_t boff = ((size_t)kb * 128 + (ntb + ni) * 16 + l15) * 8;
      f16x8 bh = *(const f16x8*)(wh + boff);
      f16x8 bl = *(const f16x8*)(wl + boff);
#pragma unroll
      for (int mi = 0; mi < 2; mi++) {
        acc[mi][ni] = __builtin_amdgcn_mfma_f32_16x16x32_f16(a_h[mi], bh, acc[mi][ni], 0, 0, 0);
        acc[mi][ni] = __builtin_amdgcn_mfma_f32_16x16x32_f16(a_h[mi], bl, acc[mi][ni], 0, 0, 0);
      }
    }
  }
  __syncthreads();   // aS dead; ot/dsrc alias safe
  if (asrc) {
#pragma unroll
    for (int mi = 0; mi < 2; mi++)
#pragma unroll
      for (int r = 0; r < 4; r++) {
        float ps = 0.f, pd = 0.f;
#pragma unroll
        for (int ni = 0; ni < 4; ni++) { ps += acc[mi][ni][r] * av[ni]; pd += acc[mi][ni][r] * bv[ni]; }
#pragma unroll
        for (int msk = 8; msk > 0; msk >>= 1) {
          ps += __shfl_xor(ps, msk, 64);
          pd += __shfl_xor(pd, msk, 64);
        }
        if (l15 == 0) {
          int row = (mtb + mi) * 16 + q * 4 + r;
          dsrc[row * 2 + (w >> 1)] = ps;
          ddst[row * 2 + (w >> 1)] = pd;
        }
      }
  }
#pragma unroll
  for (int mi = 0; mi < 2; mi++)
#pragma unroll
    for (int ni = 0; ni < 4; ni++)
#pragma unroll
      for (int r = 0; r < 4; r++)
        ot[((mtb + mi) * 16 + q * 4 + r) * 128 + (ntb + ni) * 16 + l15] = (f16)acc[mi][ni][r];
  __syncthreads();
  if (bn + ln < n) {
    f16* dst = H16 + (size_t)(bn + ln) * 128 + qt * 32;
    const f16* srcp = ot + ln * 128 + qt * 32;
#pragma unroll
    for (int jj = 0; jj < 4; jj++)
      *(f16x8*)(dst + jj * 8) = *(const f16x8*)(srcp + jj * 8);
  }
  if (asrc && tid < 64 && bn + tid < n) {
    als[bn + tid] = dsrc[tid * 2] + dsrc[tid * 2 + 1];
    ald[bn + tid] = ddst[tid * 2] + ddst[tid * 2 + 1];
  }
}

// ---------------- GCN aggregation: wave/node, f16 rows, unroll-4 ----------------
__global__ __launch_bounds__(256) void k_gcn_agg16(const f16x2* __restrict__ H2,
    const float* __restrict__ dinv, const int* __restrict__ row_ptr,
    const int* __restrict__ csr, const float* __restrict__ bias,
    float2* __restrict__ out2, f16x2* __restrict__ xh_out, int n, int leaky_flag) {
  int node = blockIdx.x * 4 + (threadIdx.x >> 6);
  int lane = threadIdx.x & 63;
  if (node >= n) return;
  int rs = row_ptr[node], re = row_ptr[node + 1];
  float dn = dinv[node];
  f16x2 sv = H2[(size_t)node * 64 + lane];
  float ax = dn * (float)sv[0], ay = dn * (float)sv[1];
  int i = rs;
  for (; i + 3 < re; i += 4) {
    int s0 = csr[i], s1 = csr[i+1], s2 = csr[i+2], s3 = csr[i+3];
    float w0 = dinv[s0], w1 = dinv[s1], w2 = dinv[s2], w3 = dinv[s3];
    f16x2 v0 = H2[(size_t)s0 * 64 + lane];
    f16x2 v1 = H2[(size_t)s1 * 64 + lane];
    f16x2 v2 = H2[(size_t)s2 * 64 + lane];
    f16x2 v3 = H2[(size_t)s3 * 64 + lane];
    ax += w0*(float)v0[0] + w1*(float)v1[0] + w2*(float)v2[0] + w3*(float)v3[0];
    ay += w0*(float)v0[1] + w1*(float)v1[1] + w2*(float)v2[1] + w3*(float)v3[1];
  }
  for (; i < re; i++) {
    int s = csr[i]; float wv = dinv[s];
    f16x2 v = H2[(size_t)s * 64 + lane];
    ax += wv * (float)v[0]; ay += wv * (float)v[1];
  }
  float2 bvv = ((const float2*)bias)[lane];
  float vx = dn * ax + bvv.x, vy = dn * ay + bvv.y;
  if (leaky_flag) { vx = lrelu(vx, 0.01f); vy = lrelu(vy, 0.01f); }
  out2[(size_t)node * 64 + lane] = make_float2(vx, vy);
  if (xh_out) { f16x2 o = { (f16)vx, (f16)vy }; xh_out[(size_t)node * 64 + lane] = o; }
}

// ---------------- GAT aggregation (denominator fused), unroll-2 ----------------
__global__ __launch_bounds__(256) void k_gat_agg16(const f16x2* __restrict__ H2,
    const float* __restrict__ als, const float* __restrict__ ald,
    const int* __restrict__ row_ptr, const int* __restrict__ csr,
    const float* __restrict__ bias, float2* __restrict__ y2, int n) {
  int node = blockIdx.x * 4 + (threadIdx.x >> 6);
  int lane = threadIdx.x & 63;
  if (node >= n) return;
  int rs = row_ptr[node], re = row_ptr[node + 1];
  float aldn = ald[node];
  float e_self = lrelu(als[node] + aldn, 0.2f);
  float mx = e_self;
  for (int i = rs + lane; i < re; i += 64) mx = fmaxf(mx, lrelu(als[csr[i]] + aldn, 0.2f));
  for (int off = 1; off < 64; off <<= 1) mx = fmaxf(mx, __shfl_xor(mx, off, 64));
  float ws = __expf(e_self - mx);
  float sm = ws;
  f16x2 sv = H2[(size_t)node * 64 + lane];
  float ax = ws * (float)sv[0], ay = ws * (float)sv[1];
  int i = rs;
  for (; i + 1 < re; i += 2) {
    int s0 = csr[i], s1 = csr[i + 1];
    float g0 = __expf(lrelu(als[s0] + aldn, 0.2f) - mx);
    float g1 = __expf(lrelu(als[s1] + aldn, 0.2f) - mx);
    f16x2 v0 = H2[(size_t)s0 * 64 + lane];
    f16x2 v1 = H2[(size_t)s1 * 64 + lane];
    sm += g0 + g1;
    ax += g0*(float)v0[0] + g1*(float)v1[0];
    ay += g0*(float)v0[1] + g1*(float)v1[1];
  }
  if (i < re) {
    int s = csr[i];
    float g = __expf(lrelu(als[s] + aldn, 0.2f) - mx);
    f16x2 v = H2[(size_t)s * 64 + lane];
    sm += g; ax += g*(float)v[0]; ay += g*(float)v[1];
  }
  float inv_s = 1.f / sm;
  float2 bvv = ((const float2*)bias)[lane];
  y2[(size_t)node * 64 + lane] = make_float2(ax * inv_s + bvv.x, ay * inv_s + bvv.y);
}

// ---------------- GraphNorm: colstats + last-block stats fusion ----------------
__global__ __launch_bounds__(256) void k_colstats(const float* __restrict__ y,
    float* __restrict__ psum, float* __restrict__ psumsq, int n, int chunk,
    const float* __restrict__ w, const float* __restrict__ bb,
    const float* __restrict__ ms, float* __restrict__ scaleA,
    float* __restrict__ shiftA, int* __restrict__ ctr) {
  int b = blockIdx.x, t = threadIdx.x;
  int c = t & 127, half = t >> 7;
  int s0 = b * chunk;
  int s1 = s0 + chunk; if (s1 > n) s1 = n;
  float s = 0.f, ss = 0.f;
  for (int i = s0 + half; i < s1; i += 2) {
    float v = y[(size_t)i * 128 + c];
    s += v; ss += v * v;
  }
  __shared__ float sh[256], sq[256];
  __shared__ int lastFlag;
  sh[t] = s; sq[t] = ss;
  __syncthreads();
  if (half == 0) {
    psum[b * 128 + c] = sh[c] + sh[c + 128];
    psumsq[b * 128 + c] = sq[c] + sq[c + 128];
  }
  __syncthreads();
  if (t == 0) {
    __threadfence();
    int v = atomicAdd(ctr, 1);
    lastFlag = (v == (int)gridDim.x - 1);
  }
  __syncthreads();
  if (!lastFlag) return;
  __threadfence();
  float S = 0.f, Q = 0.f;
  for (int bb2 = half; bb2 < 128; bb2 += 2) { S += psum[bb2 * 128 + c]; Q += psumsq[bb2 * 128 + c]; }
  sh[t] = S; sq[t] = Q;
  __syncthreads();
  if (half == 0) {
    double Sd = (double)sh[c] + (double)sh[c + 128];
    double Qd = (double)sq[c] + (double)sq[c + 128];
    double invn = 1.0 / (double)n;
    double mean = Sd * invn;
    double mt = (double)ms[c] * mean;
    double var = Qd * invn - 2.0 * mt * mean + mt * mt;
    float rstd = rsqrtf((float)var + 1e-5f);
    float sc = w[c] * rstd;
    scaleA[c] = sc;
    shiftA[c] = bb[c] - sc * (float)mt;
  }
}

// ---------------- residual (+ xh f16 emit) ----------------
__global__ __launch_bounds__(256) void k_residual(const float* __restrict__ y,
    const float* __restrict__ scaleA, const float* __restrict__ shiftA,
    float* __restrict__ x, f16x4* __restrict__ xh, int n4) {
  int i = blockIdx.x * 256 + threadIdx.x;
  if (i >= n4) return;
  int c4 = (i & 31) * 4;
  float4 yv = ((const float4*)y)[i];
  float4 xv = ((float4*)x)[i];
  float4 sc = *(const float4*)(scaleA + c4);
  float4 sh = *(const float4*)(shiftA + c4);
  xv.x += lrelu(sc.x * yv.x + sh.x, 0.01f);
  xv.y += lrelu(sc.y * yv.y + sh.y, 0.01f);
  xv.z += lrelu(sc.z * yv.z + sh.z, 0.01f);
  xv.w += lrelu(sc.w * yv.w + sh.w, 0.01f);
  ((float4*)x)[i] = xv;
  if (xh) { f16x4 o = { (f16)xv.x, (f16)xv.y, (f16)xv.z, (f16)xv.w }; xh[i] = o; }
}

// ---------------- Output head ----------------
__global__ __launch_bounds__(256) void k_dot1(const float* __restrict__ x,
                                              const float* __restrict__ wv,
                                              float* __restrict__ o, int n) {
  int node = blockIdx.x * 4 + (threadIdx.x >> 6);
  int lane = threadIdx.x & 63;
  if (node >= n) return;
  float2 hv = ((const float2*)x)[(size_t)node * 64 + lane];
  float2 v1 = ((const float2*)wv)[lane];
  float s1 = hv.x * v1.x + hv.y * v1.y;
  for (int off = 32; off > 0; off >>= 1) s1 += __shfl_down(s1, off, 64);
  if (lane == 0) o[node] = s1;
}

__global__ __launch_bounds__(256) void k_scalar_agg(const float* __restrict__ xsv,
    const float* __restrict__ dinv, const int* __restrict__ row_ptr,
    const int* __restrict__ csr, const float* __restrict__ b_out,
    float* __restrict__ xout, int n) {
  int i = blockIdx.x * 256 + threadIdx.x;
  if (i >= n) return;
  float dn = dinv[i];
  float acc = dn * xsv[i];
  int re = row_ptr[i + 1];
  for (int e = row_ptr[i]; e < re; e++) {
    int s = csr[e];
    acc += dinv[s] * xsv[s];
  }
  xout[i] = lrelu(dn * acc + b_out[0], 0.01f);
}

__global__ __launch_bounds__(256) void k_fc1(const float* __restrict__ xout,
    const float* __restrict__ fw, float* __restrict__ pfc, int n, int chunk) {
  int b = blockIdx.x, t = threadIdx.x;
  int c = t & 127, half = t >> 7;
  int s0 = b * chunk;
  int s1 = s0 + chunk; if (s1 > n) s1 = n;
  float s = 0.f;
  for (int i = s0 + half; i < s1; i += 2) s += xout[i] * fw[(size_t)i * 128 + c];
  __shared__ float sh[256];
  sh[t] = s; __syncthreads();
  if (half == 0) pfc[b * 128 + c] = sh[c] + sh[c + 128];
}

__global__ __launch_bounds__(128) void k_final(const float* __restrict__ pfc,
    const float* __restrict__ b1, const float* __restrict__ fw2,
    const float* __restrict__ b2, float* __restrict__ out) {
  int c = threadIdx.x;
  float s = 0.f;
  for (int b = 0; b < 128; b++) s += pfc[b * 128 + c];
  float hv = lrelu(s + b1[c], 0.01f);
  __shared__ float h1[128];
  h1[c] = hv; __syncthreads();
  float o = b2[c];
  for (int j = 0; j < 128; j++) o += h1[j] * fw2[j * 128 + c];
  out[c] = o;
}

// ---------------- host ----------------
extern "C" void kernel_launch(void* const* d_in, const int* in_sizes, int n_in,
                              void* d_out, int out_size, void* d_ws, size_t ws_size,
                              hipStream_t stream) {
  const int* poi      = (const int*)d_in[0];
  const float* dist   = (const float*)d_in[1];
  const int* ei       = (const int*)d_in[2];
  const float* emb    = (const float*)d_in[3];
  const float* W_in   = (const float*)d_in[4];
  const float* b_in   = (const float*)d_in[5];
  const float* gcn_W  = (const float*)d_in[6];
  const float* gcn_b  = (const float*)d_in[7];
  const float* norm_w = (const float*)d_in[8];
  const float* norm_b = (const float*)d_in[9];
  const float* norm_ms= (const float*)d_in[10];
  const float* gat_W  = (const float*)d_in[11];
  const float* gat_as = (const float*)d_in[12];
  const float* gat_ad = (const float*)d_in[13];
  const float* gat_b  = (const float*)d_in[14];
  const float* W_out  = (const float*)d_in[15];
  const float* b_out  = (const float*)d_in[16];
  const float* fc1_W  = (const float*)d_in[17];
  const float* fc1_b  = (const float*)d_in[18];
  const float* fc2_W  = (const float*)d_in[19];
  const float* fc2_b  = (const float*)d_in[20];

  const int N   = in_sizes[0] / 32;
  const int E   = in_sizes[2] / 2;
  const int POI = in_sizes[3] / 128;
  const int* srcp = ei;
  const int* dstp = ei + E;
  float* out = (float*)d_out;

  char* p = (char*)d_ws;
  auto alloc = [&](size_t bytes) { char* r = p; p += (bytes + 255) & ~(size_t)255; return r; };
  float* x   = (float*)alloc((size_t)N * 128 * 4);
  f16* h16   = (f16*)alloc((size_t)N * 128 * 2);
  f16* xh    = (f16*)alloc((size_t)N * 128 * 2);
  size_t Rneed = (size_t)POI * 128 * 2;              // f16 emb table
  size_t Ry    = (size_t)N * 128 * 4;                // y fp32 (reused after embed)
  char* R = alloc(Rneed > Ry ? Rneed : Ry);
  f16* ehalf = (f16*)R;
  float* y   = (float*)R;
  const int KBIN = 4128 / 8;                          // 516
  f16* wih = (f16*)alloc((size_t)KBIN * 128 * 8 * 2);
  f16* wil = (f16*)alloc((size_t)KBIN * 128 * 8 * 2);
  f16* wsh = (f16*)alloc((size_t)8 * 16384 * 2);
  f16* wsl = (f16*)alloc((size_t)8 * 16384 * 2);
  float* dinv   = (float*)alloc((size_t)N * 4);
  float* als    = (float*)alloc((size_t)N * 4);
  float* ald    = (float*)alloc((size_t)N * 4);
  float* xsv    = (float*)alloc((size_t)N * 4);
  float* xout   = (float*)alloc((size_t)N * 4);
  float* psum   = (float*)alloc(128 * 128 * 4);
  float* psumsq = (float*)alloc(128 * 128 * 4);
  float* pfc    = (float*)alloc(128 * 128 * 4);
  float* scaleA = (float*)alloc(128 * 4);
  float* shiftA = (float*)alloc(128 * 4);
  // deg + fill + 8 stats-counters: ONE contiguous block, one memset.
  int* deg     = (int*)alloc(((size_t)N * 2 + 8) * 4);
  int* fill    = deg + N;
  int* ctr     = deg + 2 * (size_t)N;
  int* row_ptr = (int*)alloc(((size_t)N + 1) * 4);
  int* csr     = (int*)alloc((size_t)E * 4);

  const int chunk = (N + 127) / 128;
  const int gblocks = (N + 63) / 64;
  const int eblocks = (E + 255) / 256;
  const int n4 = N * 32;
  const int nwb = (N + 3) / 4;

  hipMemsetAsync(deg, 0, sizeof(int) * (2 * (size_t)N + 8), stream);
  k_deg<<<eblocks, 256, 0, stream>>>(dstp, deg, E);
  k_scan<<<1, 1024, 0, stream>>>(deg, row_ptr, dinv, N);
  k_fill<<<eblocks, 256, 0, stream>>>(srcp, dstp, row_ptr, fill, csr, E);

  int et4 = POI * 128 / 4;
  k_conv_emb<<<(et4 + 255) / 256, 256, 0, stream>>>(emb, ehalf, et4);
  k_pack_w<<<(KBIN * 128 + 255) / 256, 256, 0, stream>>>(W_in, wih, wil, KBIN);
  k_pack_w8<<<dim3(8, 8), 256, 0, stream>>>(gcn_W, gat_W, wsh, wsl);

  // input layer
  k_mfma_embed<<<gblocks, 256, 0, stream>>>(poi, dist, ehalf, wih, wil, h16, N);
  k_gcn_agg16<<<nwb, 256, 0, stream>>>((const f16x2*)h16, dinv, row_ptr, csr, b_in,
                                       (float2*)x, (f16x2*)xh, N, 1);

  for (int l = 0; l < 4; l++) {
    const f16* gh = wsh + (size_t)l * 16384;
    const f16* gl = wsl + (size_t)l * 16384;
    const f16* th = wsh + (size_t)(4 + l) * 16384;
    const f16* tl = wsl + (size_t)(4 + l) * 16384;
    // GCN sub-unit
    k_mfma_lin<<<gblocks, 256, 0, stream>>>(xh, gh, gl, h16, N,
                                            (const float*)nullptr, (const float*)nullptr,
                                            (float*)nullptr, (float*)nullptr);
    k_gcn_agg16<<<nwb, 256, 0, stream>>>((const f16x2*)h16, dinv, row_ptr, csr,
                                         gcn_b + l * 128, (float2*)y, (f16x2*)nullptr, N, 0);
    k_colstats<<<128, 256, 0, stream>>>(y, psum, psumsq, N, chunk,
                                        norm_w + l * 128, norm_b + l * 128,
                                        norm_ms + l * 128, scaleA, shiftA, ctr + 2 * l);
    k_residual<<<(n4 + 255) / 256, 256, 0, stream>>>(y, scaleA, shiftA, x, (f16x4*)xh, n4);
    // GAT sub-unit (dot2 fused into lin epilogue)
    k_mfma_lin<<<gblocks, 256, 0, stream>>>(xh, th, tl, h16, N,
                                            gat_as + l * 128, gat_ad + l * 128, als, ald);
    k_gat_agg16<<<nwb, 256, 0, stream>>>((const f16x2*)h16, als, ald, row_ptr, csr,
                                         gat_b + l * 128, (float2*)y, N);
    k_colstats<<<128, 256, 0, stream>>>(y, psum, psumsq, N, chunk,
                                        norm_w + l * 128, norm_b + l * 128,
                                        norm_ms + l * 128, scaleA, shiftA, ctr + 2 * l + 1);
    k_residual<<<(n4 + 255) / 256, 256, 0, stream>>>(y, scaleA, shiftA, x,
        (l == 3) ? (f16x4*)nullptr : (f16x4*)xh, n4);
  }

  // output head
  k_dot1<<<nwb, 256, 0, stream>>>(x, W_out, xsv, N);
  k_scalar_agg<<<(N + 255) / 256, 256, 0, stream>>>(xsv, dinv, row_ptr, csr, b_out, xout, N);
  k_fc1<<<128, 256, 0, stream>>>(xout, fc1_W, pfc, N, chunk);
  k_final<<<1, 128, 0, stream>>>(pfc, fc1_b, fc2_W, fc2_b, out);
}

// Round 6
// 1439.588 us; speedup vs baseline: 1.6330x; 1.0960x over previous
//
#include <hip/hip_runtime.h>

// GlobalDistNet forward, round 6:
//  - embed GEMM: single-f16 W (halves B traffic + MFMA; r5 had 4x absmax headroom),
//    512-thread block = two 4-wave K-halves with LDS merge (r5 was grid-limited
//    at 2.34 blocks/CU -> latency-bound, all pipes <15%)
//  - GCN/scalar aggs: precomputed per-edge weights csrw (kills dependent dinv load)
//  - GAT agg: unroll 4
//  - lin GEMMs keep f16 hi+lo (accuracy), as r5

typedef _Float16 f16;
typedef f16 f16x8 __attribute__((ext_vector_type(8)));
typedef f16 f16x4 __attribute__((ext_vector_type(4)));
typedef f16 f16x2 __attribute__((ext_vector_type(2)));
typedef float f32x4 __attribute__((ext_vector_type(4)));

__device__ __forceinline__ float lrelu(float x, float s){ return x>=0.f? x : s*x; }

// ---------------- CSR build ----------------
__global__ __launch_bounds__(256) void k_deg(const int* __restrict__ dst,
                                             int* __restrict__ deg, int E) {
  int i = blockIdx.x * 256 + threadIdx.x;
  if (i < E) atomicAdd(&deg[dst[i]], 1);
}

__global__ __launch_bounds__(1024) void k_scan(const int* __restrict__ deg,
                                               int* __restrict__ row_ptr,
                                               float* __restrict__ dinv, int n) {
  __shared__ int sd[1024];
  __shared__ int sbase;
  int t = threadIdx.x;
  if (t == 0) { sbase = 0; row_ptr[0] = 0; }
  __syncthreads();
  for (int start = 0; start < n; start += 1024) {
    int i = start + t;
    int v = (i < n) ? deg[i] : 0;
    if (i < n) dinv[i] = rsqrtf((float)(v + 1));
    sd[t] = v;
    __syncthreads();
    for (int off = 1; off < 1024; off <<= 1) {
      int other = (t >= off) ? sd[t - off] : 0;
      __syncthreads();
      sd[t] += other;
      __syncthreads();
    }
    int base = sbase;
    if (i < n) row_ptr[i + 1] = base + sd[t];
    __syncthreads();
    if (t == 1023) sbase = base + sd[1023];
    __syncthreads();
  }
}

// fill csr + per-edge gcn weight dinv[d]*dinv[s]
__global__ __launch_bounds__(256) void k_fill(const int* __restrict__ src,
                                              const int* __restrict__ dst,
                                              const int* __restrict__ row_ptr,
                                              const float* __restrict__ dinv,
                                              int* __restrict__ fill,
                                              int* __restrict__ csr,
                                              float* __restrict__ csrw, int E) {
  int i = blockIdx.x * 256 + threadIdx.x;
  if (i < E) {
    int d = dst[i], s = src[i];
    int pos = row_ptr[d] + atomicAdd(&fill[d], 1);
    csr[pos] = s;
    csrw[pos] = dinv[d] * dinv[s];
  }
}

// ---------------- conversions / packing ----------------
__global__ __launch_bounds__(256) void k_conv_emb(const float* __restrict__ src,
                                                  f16* __restrict__ dst, int total4) {
  int i = blockIdx.x * 256 + threadIdx.x;
  if (i >= total4) return;
  float4 v = ((const float4*)src)[i];
  f16x4 o = { (f16)v.x, (f16)v.y, (f16)v.z, (f16)v.w };
  ((f16x4*)dst)[i] = o;
}

// W_in [K][128] fp32 -> [K/8][128][8] f16 single (embed GEMM B layout)
__global__ __launch_bounds__(256) void k_pack_w(const float* __restrict__ W,
    f16* __restrict__ hi, int kb_total) {
  int idx = blockIdx.x * 256 + threadIdx.x;
  int c = idx & 127, kb = idx >> 7;
  if (kb >= kb_total) return;
  f16x8 hv;
#pragma unroll
  for (int j = 0; j < 8; j++) hv[j] = (f16)W[(size_t)(kb*8 + j) * 128 + c];
  ((f16x8*)hi)[idx] = hv;
}

// 8 small 128x128 matrices (4 gcn + 4 gat) hi/lo; grid (8, 8)
__global__ __launch_bounds__(256) void k_pack_w8(const float* __restrict__ gcnW,
    const float* __restrict__ gatW, f16* __restrict__ hi, f16* __restrict__ lo) {
  int mat = blockIdx.y;
  const float* W = (mat < 4) ? gcnW + (size_t)mat * 16384 : gatW + (size_t)(mat - 4) * 16384;
  int idx = blockIdx.x * 256 + threadIdx.x;
  int c = idx & 127, kb = idx >> 7;
  f16x8 hv, lv;
#pragma unroll
  for (int j = 0; j < 8; j++) {
    float v = W[(size_t)(kb*8 + j) * 128 + c];
    f16 h = (f16)v;
    hv[j] = h; lv[j] = (f16)(v - (float)h);
  }
  ((f16x8*)hi)[mat * 2048 + idx] = hv;
  ((f16x8*)lo)[mat * 2048 + idx] = lv;
}

// ---------------- MFMA GEMM: embed-gather A, K=4128, dual K-half block ------------
// 512 threads = 2 halves x 4 waves. Half h processes poi slots j in [16h, 16h+16),
// half 1 also does the distance chunk. Accumulators merged through LDS at the end.
#define APAD 152
__global__ __launch_bounds__(512) void k_mfma_embed(const int* __restrict__ poi,
    const float* __restrict__ dist, const f16* __restrict__ eh,
    const f16* __restrict__ wh, f16* __restrict__ H16, int n) {
  __shared__ __attribute__((aligned(16))) char smem[49152];
  int* poi_s = (int*)smem;                 // [2][16][64] = 8 KB
  f16* aS    = (f16*)(smem + 8192);        // [2][64][APAD] = 38912 B
  f16* OT    = (f16*)smem;                 // [64][128] f16 (epilogue alias)
  float* F   = (float*)(smem + 16384);     // [64][128] f32 (epilogue alias)
  int tid = threadIdx.x;
  int bn = blockIdx.x * 64;
  int half = tid >> 8;
  int t2 = tid & 255;
  int ln = t2 >> 2, qt = t2 & 3;
  int xrow = bn + ln; if (xrow > n - 1) xrow = n - 1;
  {
#pragma unroll
    for (int jj = 0; jj < 4; jj++)
      poi_s[half * 1024 + (qt * 4 + jj) * 64 + ln] =
        poi[(size_t)xrow * 32 + half * 16 + qt * 4 + jj];
  }
  int w2 = (tid >> 6) & 3, lane = tid & 63;
  int q = lane >> 4, l15 = lane & 15;
  int mtb = (w2 & 1) * 2;
  int ntb = (w2 >> 1) * 4;
  f16* aH = aS + half * 64 * APAD;
  f32x4 acc[2][4];
#pragma unroll
  for (int a = 0; a < 2; a++)
#pragma unroll
    for (int b = 0; b < 4; b++) { acc[a][b][0]=0.f; acc[a][b][1]=0.f; acc[a][b][2]=0.f; acc[a][b][3]=0.f; }
  __syncthreads();   // poi_s ready

  f16x8 r0, r1, r2, r3;
  {
    const f16* srcp = eh + (size_t)poi_s[half * 1024 + ln] * 128 + qt * 32;
    r0 = *(const f16x8*)(srcp);      r1 = *(const f16x8*)(srcp + 8);
    r2 = *(const f16x8*)(srcp + 16); r3 = *(const f16x8*)(srcp + 24);
  }

#pragma unroll 1
  for (int j = 0; j < 16; j++) {
    __syncthreads();
    f16* wp = aH + ln * APAD + qt * 32;
    *(f16x8*)(wp) = r0; *(f16x8*)(wp + 8) = r1;
    *(f16x8*)(wp + 16) = r2; *(f16x8*)(wp + 24) = r3;
    if (j + 1 < 16) {
      const f16* srcp = eh + (size_t)poi_s[half * 1024 + (j + 1) * 64 + ln] * 128 + qt * 32;
      r0 = *(const f16x8*)(srcp);      r1 = *(const f16x8*)(srcp + 8);
      r2 = *(const f16x8*)(srcp + 16); r3 = *(const f16x8*)(srcp + 24);
    }
    __syncthreads();
#pragma unroll
    for (int kcl = 0; kcl < 4; kcl++) {
      f16x8 a_h[2];
#pragma unroll
      for (int mi = 0; mi < 2; mi++)
        a_h[mi] = *(const f16x8*)(aH + ((mtb + mi) * 16 + l15) * APAD + kcl * 32 + q * 8);
      int kb = (half * 16 + j) * 16 + kcl * 4 + q;
#pragma unroll
      for (int ni = 0; ni < 4; ni++) {
        f16x8 bh = *(const f16x8*)(wh + ((size_t)kb * 128 + (ntb + ni) * 16 + l15) * 8);
#pragma unroll
        for (int mi = 0; mi < 2; mi++)
          acc[mi][ni] = __builtin_amdgcn_mfma_f32_16x16x32_f16(a_h[mi], bh, acc[mi][ni], 0, 0, 0);
      }
    }
  }
  if (half) {   // distance chunk k=4096..4127 (no barriers inside)
    int nc0 = bn + (mtb + 0) * 16 + l15; if (nc0 > n - 1) nc0 = n - 1;
    int nc1 = bn + (mtb + 1) * 16 + l15; if (nc1 > n - 1) nc1 = n - 1;
    f16x8 ad[2];
#pragma unroll
    for (int mi = 0; mi < 2; mi++) {
      int nc = mi ? nc1 : nc0;
      const float* dp = dist + (size_t)nc * 32 + q * 8;
      float4 d0 = *(const float4*)dp, d1 = *(const float4*)(dp + 4);
      ad[mi][0]=(f16)d0.x; ad[mi][1]=(f16)d0.y; ad[mi][2]=(f16)d0.z; ad[mi][3]=(f16)d0.w;
      ad[mi][4]=(f16)d1.x; ad[mi][5]=(f16)d1.y; ad[mi][6]=(f16)d1.z; ad[mi][7]=(f16)d1.w;
    }
    int kb = 512 + q;
#pragma unroll
    for (int ni = 0; ni < 4; ni++) {
      f16x8 bh = *(const f16x8*)(wh + ((size_t)kb * 128 + (ntb + ni) * 16 + l15) * 8);
#pragma unroll
      for (int mi = 0; mi < 2; mi++)
        acc[mi][ni] = __builtin_amdgcn_mfma_f32_16x16x32_f16(ad[mi], bh, acc[mi][ni], 0, 0, 0);
    }
  }
  // merge halves + f16 epilogue
  __syncthreads();
  if (half) {
#pragma unroll
    for (int mi = 0; mi < 2; mi++)
#pragma unroll
      for (int ni = 0; ni < 4; ni++)
#pragma unroll
        for (int r = 0; r < 4; r++)
          F[((mtb + mi) * 16 + q * 4 + r) * 128 + (ntb + ni) * 16 + l15] = acc[mi][ni][r];
  }
  __syncthreads();
  if (!half) {
#pragma unroll
    for (int mi = 0; mi < 2; mi++)
#pragma unroll
      for (int ni = 0; ni < 4; ni++)
#pragma unroll
        for (int r = 0; r < 4; r++) {
          int o = ((mtb + mi) * 16 + q * 4 + r) * 128 + (ntb + ni) * 16 + l15;
          OT[o] = (f16)(acc[mi][ni][r] + F[o]);
        }
  }
  __syncthreads();
#pragma unroll
  for (int ch = 0; ch < 2; ch++) {
    int c1024 = tid + ch * 512;
    int row = c1024 >> 4, c8 = c1024 & 15;
    if (bn + row < n)
      *(f16x8*)(H16 + (size_t)(bn + row) * 128 + c8 * 8) = *(const f16x8*)(OT + row * 128 + c8 * 8);
  }
}

// ---------------- MFMA GEMM: f16 A (xh), K=128; optional fused a-dot epilogue ----
#define LPAD 136
__global__ __launch_bounds__(256) void k_mfma_lin(const f16* __restrict__ XH,
    const f16* __restrict__ wh, const f16* __restrict__ wl,
    f16* __restrict__ H16, int n,
    const float* __restrict__ asrc, const float* __restrict__ adst,
    float* __restrict__ als, float* __restrict__ ald) {
  __shared__ __attribute__((aligned(16))) char smem[64 * LPAD * 2];
  f16* aS = (f16*)smem;
  f16* ot = (f16*)smem;
  float* dsrc = (float*)(smem + 16384);
  float* ddst = (float*)(smem + 16896);
  int tid = threadIdx.x;
  int bn = blockIdx.x * 64;
  int ln = tid >> 2, qt = tid & 3;
  int xrow = bn + ln; if (xrow > n - 1) xrow = n - 1;
  int w = tid >> 6, lane = tid & 63;
  int q = lane >> 4, l15 = lane & 15;
  int mtb = (w & 1) * 2;
  int ntb = (w >> 1) * 4;
  {
    const f16* srcp = XH + (size_t)xrow * 128 + qt * 32;
    f16* wp = aS + ln * LPAD + qt * 32;
    *(f16x8*)(wp)      = *(const f16x8*)(srcp);
    *(f16x8*)(wp + 8)  = *(const f16x8*)(srcp + 8);
    *(f16x8*)(wp + 16) = *(const f16x8*)(srcp + 16);
    *(f16x8*)(wp + 24) = *(const f16x8*)(srcp + 24);
  }
  float av[4], bv[4];
  if (asrc) {
#pragma unroll
    for (int ni = 0; ni < 4; ni++) {
      av[ni] = asrc[(ntb + ni) * 16 + l15];
      bv[ni] = adst[(ntb + ni) * 16 + l15];
    }
  }
  f32x4 acc[2][4];
#pragma unroll
  for (int a = 0; a < 2; a++)
#pragma unroll
    for (int b = 0; b < 4; b++) { acc[a][b][0]=0.f; acc[a][b][1]=0.f; acc[a][b][2]=0.f; acc[a][b][3]=0.f; }
  __syncthreads();
#pragma unroll
  for (int kcl = 0; kcl < 4; kcl++) {
    f16x8 a_h[2];
#pragma unroll
    for (int mi = 0; mi < 2; mi++)
      a_h[mi] = *(const f16x8*)(aS + ((mtb + mi) * 16 + l15) * LPAD + kcl * 32 + q * 8);
    int kb = kcl * 4 + q;
#pragma unroll
    for (int ni = 0; ni < 4; ni++) {
      size_t boff = ((size_t)kb * 128 + (ntb + ni) * 16 + l15) * 8;
      f16x8 bh = *(const f16x8*)(wh + boff);
      f16x8 bl = *(const f16x8*)(wl + boff);
#pragma unroll
      for (int mi = 0; mi < 2; mi++) {
        acc[mi][ni] = __builtin_amdgcn_mfma_f32_16x16x32_f16(a_h[mi], bh, acc[mi][ni], 0, 0, 0);
        acc[mi][ni] = __builtin_amdgcn_mfma_f32_16x16x32_f16(a_h[mi], bl, acc[mi][ni], 0, 0, 0);
      }
    }
  }
  __syncthreads();
  if (asrc) {
#pragma unroll
    for (int mi = 0; mi < 2; mi++)
#pragma unroll
      for (int r = 0; r < 4; r++) {
        float ps = 0.f, pd = 0.f;
#pragma unroll
        for (int ni = 0; ni < 4; ni++) { ps += acc[mi][ni][r] * av[ni]; pd += acc[mi][ni][r] * bv[ni]; }
#pragma unroll
        for (int msk = 8; msk > 0; msk >>= 1) {
          ps += __shfl_xor(ps, msk, 64);
          pd += __shfl_xor(pd, msk, 64);
        }
        if (l15 == 0) {
          int row = (mtb + mi) * 16 + q * 4 + r;
          dsrc[row * 2 + (w >> 1)] = ps;
          ddst[row * 2 + (w >> 1)] = pd;
        }
      }
  }
#pragma unroll
  for (int mi = 0; mi < 2; mi++)
#pragma unroll
    for (int ni = 0; ni < 4; ni++)
#pragma unroll
      for (int r = 0; r < 4; r++)
        ot[((mtb + mi) * 16 + q * 4 + r) * 128 + (ntb + ni) * 16 + l15] = (f16)acc[mi][ni][r];
  __syncthreads();
  if (bn + ln < n) {
    f16* dst = H16 + (size_t)(bn + ln) * 128 + qt * 32;
    const f16* srcp = ot + ln * 128 + qt * 32;
#pragma unroll
    for (int jj = 0; jj < 4; jj++)
      *(f16x8*)(dst + jj * 8) = *(const f16x8*)(srcp + jj * 8);
  }
  if (asrc && tid < 64 && bn + tid < n) {
    als[bn + tid] = dsrc[tid * 2] + dsrc[tid * 2 + 1];
    ald[bn + tid] = ddst[tid * 2] + ddst[tid * 2 + 1];
  }
}

// ---------------- GCN aggregation: wave/node, precomputed edge weights ----------
__global__ __launch_bounds__(256) void k_gcn_agg16(const f16x2* __restrict__ H2,
    const float* __restrict__ dinv, const int* __restrict__ row_ptr,
    const int* __restrict__ csr, const float* __restrict__ csrw,
    const float* __restrict__ bias,
    float2* __restrict__ out2, f16x2* __restrict__ xh_out, int n, int leaky_flag) {
  int node = blockIdx.x * 4 + (threadIdx.x >> 6);
  int lane = threadIdx.x & 63;
  if (node >= n) return;
  int rs = row_ptr[node], re = row_ptr[node + 1];
  float dn = dinv[node];
  f16x2 sv = H2[(size_t)node * 64 + lane];
  float ws0 = dn * dn;
  float ax = ws0 * (float)sv[0], ay = ws0 * (float)sv[1];
  int i = rs;
  for (; i + 3 < re; i += 4) {
    int s0 = csr[i], s1 = csr[i+1], s2 = csr[i+2], s3 = csr[i+3];
    float w0 = csrw[i], w1 = csrw[i+1], w2 = csrw[i+2], w3 = csrw[i+3];
    f16x2 v0 = H2[(size_t)s0 * 64 + lane];
    f16x2 v1 = H2[(size_t)s1 * 64 + lane];
    f16x2 v2 = H2[(size_t)s2 * 64 + lane];
    f16x2 v3 = H2[(size_t)s3 * 64 + lane];
    ax += w0*(float)v0[0] + w1*(float)v1[0] + w2*(float)v2[0] + w3*(float)v3[0];
    ay += w0*(float)v0[1] + w1*(float)v1[1] + w2*(float)v2[1] + w3*(float)v3[1];
  }
  for (; i < re; i++) {
    int s = csr[i]; float wv = csrw[i];
    f16x2 v = H2[(size_t)s * 64 + lane];
    ax += wv * (float)v[0]; ay += wv * (float)v[1];
  }
  float2 bvv = ((const float2*)bias)[lane];
  float vx = ax + bvv.x, vy = ay + bvv.y;
  if (leaky_flag) { vx = lrelu(vx, 0.01f); vy = lrelu(vy, 0.01f); }
  out2[(size_t)node * 64 + lane] = make_float2(vx, vy);
  if (xh_out) { f16x2 o = { (f16)vx, (f16)vy }; xh_out[(size_t)node * 64 + lane] = o; }
}

// ---------------- GAT aggregation (denominator fused), unroll-4 ----------------
__global__ __launch_bounds__(256) void k_gat_agg16(const f16x2* __restrict__ H2,
    const float* __restrict__ als, const float* __restrict__ ald,
    const int* __restrict__ row_ptr, const int* __restrict__ csr,
    const float* __restrict__ bias, float2* __restrict__ y2, int n) {
  int node = blockIdx.x * 4 + (threadIdx.x >> 6);
  int lane = threadIdx.x & 63;
  if (node >= n) return;
  int rs = row_ptr[node], re = row_ptr[node + 1];
  float aldn = ald[node];
  float e_self = lrelu(als[node] + aldn, 0.2f);
  float mx = e_self;
  for (int i = rs + lane; i < re; i += 64) mx = fmaxf(mx, lrelu(als[csr[i]] + aldn, 0.2f));
  for (int off = 1; off < 64; off <<= 1) mx = fmaxf(mx, __shfl_xor(mx, off, 64));
  float ws = __expf(e_self - mx);
  float sm = ws;
  f16x2 sv = H2[(size_t)node * 64 + lane];
  float ax = ws * (float)sv[0], ay = ws * (float)sv[1];
  int i = rs;
  for (; i + 3 < re; i += 4) {
    int s0 = csr[i], s1 = csr[i+1], s2 = csr[i+2], s3 = csr[i+3];
    float g0 = __expf(lrelu(als[s0] + aldn, 0.2f) - mx);
    float g1 = __expf(lrelu(als[s1] + aldn, 0.2f) - mx);
    float g2 = __expf(lrelu(als[s2] + aldn, 0.2f) - mx);
    float g3 = __expf(lrelu(als[s3] + aldn, 0.2f) - mx);
    f16x2 v0 = H2[(size_t)s0 * 64 + lane];
    f16x2 v1 = H2[(size_t)s1 * 64 + lane];
    f16x2 v2 = H2[(size_t)s2 * 64 + lane];
    f16x2 v3 = H2[(size_t)s3 * 64 + lane];
    sm += (g0 + g1) + (g2 + g3);
    ax += g0*(float)v0[0] + g1*(float)v1[0] + g2*(float)v2[0] + g3*(float)v3[0];
    ay += g0*(float)v0[1] + g1*(float)v1[1] + g2*(float)v2[1] + g3*(float)v3[1];
  }
  for (; i < re; i++) {
    int s = csr[i];
    float g = __expf(lrelu(als[s] + aldn, 0.2f) - mx);
    f16x2 v = H2[(size_t)s * 64 + lane];
    sm += g; ax += g*(float)v[0]; ay += g*(float)v[1];
  }
  float inv_s = 1.f / sm;
  float2 bvv = ((const float2*)bias)[lane];
  y2[(size_t)node * 64 + lane] = make_float2(ax * inv_s + bvv.x, ay * inv_s + bvv.y);
}

// ---------------- GraphNorm: colstats + last-block stats fusion ----------------
__global__ __launch_bounds__(256) void k_colstats(const float* __restrict__ y,
    float* __restrict__ psum, float* __restrict__ psumsq, int n, int chunk,
    const float* __restrict__ w, const float* __restrict__ bb,
    const float* __restrict__ ms, float* __restrict__ scaleA,
    float* __restrict__ shiftA, int* __restrict__ ctr) {
  int b = blockIdx.x, t = threadIdx.x;
  int c = t & 127, half = t >> 7;
  int s0 = b * chunk;
  int s1 = s0 + chunk; if (s1 > n) s1 = n;
  float s = 0.f, ss = 0.f;
  for (int i = s0 + half; i < s1; i += 2) {
    float v = y[(size_t)i * 128 + c];
    s += v; ss += v * v;
  }
  __shared__ float sh[256], sq[256];
  __shared__ int lastFlag;
  sh[t] = s; sq[t] = ss;
  __syncthreads();
  if (half == 0) {
    psum[b * 128 + c] = sh[c] + sh[c + 128];
    psumsq[b * 128 + c] = sq[c] + sq[c + 128];
  }
  __syncthreads();
  if (t == 0) {
    __threadfence();
    int v = atomicAdd(ctr, 1);
    lastFlag = (v == (int)gridDim.x - 1);
  }
  __syncthreads();
  if (!lastFlag) return;
  __threadfence();
  float S = 0.f, Q = 0.f;
  for (int bb2 = half; bb2 < 128; bb2 += 2) { S += psum[bb2 * 128 + c]; Q += psumsq[bb2 * 128 + c]; }
  sh[t] = S; sq[t] = Q;
  __syncthreads();
  if (half == 0) {
    double Sd = (double)sh[c] + (double)sh[c + 128];
    double Qd = (double)sq[c] + (double)sq[c + 128];
    double invn = 1.0 / (double)n;
    double mean = Sd * invn;
    double mt = (double)ms[c] * mean;
    double var = Qd * invn - 2.0 * mt * mean + mt * mt;
    float rstd = rsqrtf((float)var + 1e-5f);
    float sc = w[c] * rstd;
    scaleA[c] = sc;
    shiftA[c] = bb[c] - sc * (float)mt;
  }
}

// ---------------- residual (+ xh f16 emit) ----------------
__global__ __launch_bounds__(256) void k_residual(const float* __restrict__ y,
    const float* __restrict__ scaleA, const float* __restrict__ shiftA,
    float* __restrict__ x, f16x4* __restrict__ xh, int n4) {
  int i = blockIdx.x * 256 + threadIdx.x;
  if (i >= n4) return;
  int c4 = (i & 31) * 4;
  float4 yv = ((const float4*)y)[i];
  float4 xv = ((float4*)x)[i];
  float4 sc = *(const float4*)(scaleA + c4);
  float4 sh = *(const float4*)(shiftA + c4);
  xv.x += lrelu(sc.x * yv.x + sh.x, 0.01f);
  xv.y += lrelu(sc.y * yv.y + sh.y, 0.01f);
  xv.z += lrelu(sc.z * yv.z + sh.z, 0.01f);
  xv.w += lrelu(sc.w * yv.w + sh.w, 0.01f);
  ((float4*)x)[i] = xv;
  if (xh) { f16x4 o = { (f16)xv.x, (f16)xv.y, (f16)xv.z, (f16)xv.w }; xh[i] = o; }
}

// ---------------- Output head ----------------
__global__ __launch_bounds__(256) void k_dot1(const float* __restrict__ x,
                                              const float* __restrict__ wv,
                                              float* __restrict__ o, int n) {
  int node = blockIdx.x * 4 + (threadIdx.x >> 6);
  int lane = threadIdx.x & 63;
  if (node >= n) return;
  float2 hv = ((const float2*)x)[(size_t)node * 64 + lane];
  float2 v1 = ((const float2*)wv)[lane];
  float s1 = hv.x * v1.x + hv.y * v1.y;
  for (int off = 32; off > 0; off >>= 1) s1 += __shfl_down(s1, off, 64);
  if (lane == 0) o[node] = s1;
}

__global__ __launch_bounds__(256) void k_scalar_agg(const float* __restrict__ xsv,
    const float* __restrict__ dinv, const int* __restrict__ row_ptr,
    const int* __restrict__ csr, const float* __restrict__ csrw,
    const float* __restrict__ b_out, float* __restrict__ xout, int n) {
  int i = blockIdx.x * 256 + threadIdx.x;
  if (i >= n) return;
  float dn = dinv[i];
  float acc = dn * dn * xsv[i];
  int re = row_ptr[i + 1];
  for (int e = row_ptr[i]; e < re; e++)
    acc += csrw[e] * xsv[csr[e]];
  xout[i] = lrelu(acc + b_out[0], 0.01f);
}

__global__ __launch_bounds__(256) void k_fc1(const float* __restrict__ xout,
    const float* __restrict__ fw, float* __restrict__ pfc, int n, int chunk) {
  int b = blockIdx.x, t = threadIdx.x;
  int c = t & 127, half = t >> 7;
  int s0 = b * chunk;
  int s1 = s0 + chunk; if (s1 > n) s1 = n;
  float s = 0.f;
  for (int i = s0 + half; i < s1; i += 2) s += xout[i] * fw[(size_t)i * 128 + c];
  __shared__ float sh[256];
  sh[t] = s; __syncthreads();
  if (half == 0) pfc[b * 128 + c] = sh[c] + sh[c + 128];
}

__global__ __launch_bounds__(128) void k_final(const float* __restrict__ pfc,
    const float* __restrict__ b1, const float* __restrict__ fw2,
    const float* __restrict__ b2, float* __restrict__ out) {
  int c = threadIdx.x;
  float s = 0.f;
  for (int b = 0; b < 128; b++) s += pfc[b * 128 + c];
  float hv = lrelu(s + b1[c], 0.01f);
  __shared__ float h1[128];
  h1[c] = hv; __syncthreads();
  float o = b2[c];
  for (int j = 0; j < 128; j++) o += h1[j] * fw2[j * 128 + c];
  out[c] = o;
}

// ---------------- host ----------------
extern "C" void kernel_launch(void* const* d_in, const int* in_sizes, int n_in,
                              void* d_out, int out_size, void* d_ws, size_t ws_size,
                              hipStream_t stream) {
  const int* poi      = (const int*)d_in[0];
  const float* dist   = (const float*)d_in[1];
  const int* ei       = (const int*)d_in[2];
  const float* emb    = (const float*)d_in[3];
  const float* W_in   = (const float*)d_in[4];
  const float* b_in   = (const float*)d_in[5];
  const float* gcn_W  = (const float*)d_in[6];
  const float* gcn_b  = (const float*)d_in[7];
  const float* norm_w = (const float*)d_in[8];
  const float* norm_b = (const float*)d_in[9];
  const float* norm_ms= (const float*)d_in[10];
  const float* gat_W  = (const float*)d_in[11];
  const float* gat_as = (const float*)d_in[12];
  const float* gat_ad = (const float*)d_in[13];
  const float* gat_b  = (const float*)d_in[14];
  const float* W_out  = (const float*)d_in[15];
  const float* b_out  = (const float*)d_in[16];
  const float* fc1_W  = (const float*)d_in[17];
  const float* fc1_b  = (const float*)d_in[18];
  const float* fc2_W  = (const float*)d_in[19];
  const float* fc2_b  = (const float*)d_in[20];

  const int N   = in_sizes[0] / 32;
  const int E   = in_sizes[2] / 2;
  const int POI = in_sizes[3] / 128;
  const int* srcp = ei;
  const int* dstp = ei + E;
  float* out = (float*)d_out;

  char* p = (char*)d_ws;
  auto alloc = [&](size_t bytes) { char* r = p; p += (bytes + 255) & ~(size_t)255; return r; };
  float* x   = (float*)alloc((size_t)N * 128 * 4);
  f16* h16   = (f16*)alloc((size_t)N * 128 * 2);
  f16* xh    = (f16*)alloc((size_t)N * 128 * 2);
  size_t Rneed = (size_t)POI * 128 * 2;              // f16 emb table
  size_t Ry    = (size_t)N * 128 * 4;                // y fp32 (reused after embed)
  char* R = alloc(Rneed > Ry ? Rneed : Ry);
  f16* ehalf = (f16*)R;
  float* y   = (float*)R;
  const int KBIN = 4128 / 8;                          // 516
  f16* wih = (f16*)alloc((size_t)KBIN * 128 * 8 * 2); // embed W, f16 single
  f16* wsh = (f16*)alloc((size_t)8 * 16384 * 2);
  f16* wsl = (f16*)alloc((size_t)8 * 16384 * 2);
  float* dinv   = (float*)alloc((size_t)N * 4);
  float* als    = (float*)alloc((size_t)N * 4);
  float* ald    = (float*)alloc((size_t)N * 4);
  float* xsv    = (float*)alloc((size_t)N * 4);
  float* xout   = (float*)alloc((size_t)N * 4);
  float* psum   = (float*)alloc(128 * 128 * 4);
  float* psumsq = (float*)alloc(128 * 128 * 4);
  float* pfc    = (float*)alloc(128 * 128 * 4);
  float* scaleA = (float*)alloc(128 * 4);
  float* shiftA = (float*)alloc(128 * 4);
  // deg + fill + 8 stats-counters: ONE contiguous block, one memset.
  int* deg     = (int*)alloc(((size_t)N * 2 + 8) * 4);
  int* fill    = deg + N;
  int* ctr     = deg + 2 * (size_t)N;
  int* row_ptr = (int*)alloc(((size_t)N + 1) * 4);
  int* csr     = (int*)alloc((size_t)E * 4);
  float* csrw  = (float*)alloc((size_t)E * 4);

  const int chunk = (N + 127) / 128;
  const int gblocks = (N + 63) / 64;
  const int eblocks = (E + 255) / 256;
  const int n4 = N * 32;
  const int nwb = (N + 3) / 4;

  hipMemsetAsync(deg, 0, sizeof(int) * (2 * (size_t)N + 8), stream);
  k_deg<<<eblocks, 256, 0, stream>>>(dstp, deg, E);
  k_scan<<<1, 1024, 0, stream>>>(deg, row_ptr, dinv, N);
  k_fill<<<eblocks, 256, 0, stream>>>(srcp, dstp, row_ptr, dinv, fill, csr, csrw, E);

  int et4 = POI * 128 / 4;
  k_conv_emb<<<(et4 + 255) / 256, 256, 0, stream>>>(emb, ehalf, et4);
  k_pack_w<<<(KBIN * 128 + 255) / 256, 256, 0, stream>>>(W_in, wih, KBIN);
  k_pack_w8<<<dim3(8, 8), 256, 0, stream>>>(gcn_W, gat_W, wsh, wsl);

  // input layer
  k_mfma_embed<<<gblocks, 512, 0, stream>>>(poi, dist, ehalf, wih, h16, N);
  k_gcn_agg16<<<nwb, 256, 0, stream>>>((const f16x2*)h16, dinv, row_ptr, csr, csrw, b_in,
                                       (float2*)x, (f16x2*)xh, N, 1);

  for (int l = 0; l < 4; l++) {
    const f16* gh = wsh + (size_t)l * 16384;
    const f16* gl = wsl + (size_t)l * 16384;
    const f16* th = wsh + (size_t)(4 + l) * 16384;
    const f16* tl = wsl + (size_t)(4 + l) * 16384;
    // GCN sub-unit
    k_mfma_lin<<<gblocks, 256, 0, stream>>>(xh, gh, gl, h16, N,
                                            (const float*)nullptr, (const float*)nullptr,
                                            (float*)nullptr, (float*)nullptr);
    k_gcn_agg16<<<nwb, 256, 0, stream>>>((const f16x2*)h16, dinv, row_ptr, csr, csrw,
                                         gcn_b + l * 128, (float2*)y, (f16x2*)nullptr, N, 0);
    k_colstats<<<128, 256, 0, stream>>>(y, psum, psumsq, N, chunk,
                                        norm_w + l * 128, norm_b + l * 128,
                                        norm_ms + l * 128, scaleA, shiftA, ctr + 2 * l);
    k_residual<<<(n4 + 255) / 256, 256, 0, stream>>>(y, scaleA, shiftA, x, (f16x4*)xh, n4);
    // GAT sub-unit (dot2 fused into lin epilogue)
    k_mfma_lin<<<gblocks, 256, 0, stream>>>(xh, th, tl, h16, N,
                                            gat_as + l * 128, gat_ad + l * 128, als, ald);
    k_gat_agg16<<<nwb, 256, 0, stream>>>((const f16x2*)h16, als, ald, row_ptr, csr,
                                         gat_b + l * 128, (float2*)y, N);
    k_colstats<<<128, 256, 0, stream>>>(y, psum, psumsq, N, chunk,
                                        norm_w + l * 128, norm_b + l * 128,
                                        norm_ms + l * 128, scaleA, shiftA, ctr + 2 * l + 1);
    k_residual<<<(n4 + 255) / 256, 256, 0, stream>>>(y, scaleA, shiftA, x,
        (l == 3) ? (f16x4*)nullptr : (f16x4*)xh, n4);
  }

  // output head
  k_dot1<<<nwb, 256, 0, stream>>>(x, W_out, xsv, N);
  k_scalar_agg<<<(N + 255) / 256, 256, 0, stream>>>(xsv, dinv, row_ptr, csr, csrw, b_out, xout, N);
  k_fc1<<<128, 256, 0, stream>>>(xout, fc1_W, pfc, N, chunk);
  k_final<<<1, 128, 0, stream>>>(pfc, fc1_b, fc2_W, fc2_b, out);
}

// Round 7
// 1010.057 us; speedup vs baseline: 2.3274x; 1.4253x over previous
//
#include <hip/hip_runtime.h>

// GlobalDistNet forward, round 7:
//  - staged-shuffle aggregations: 64-wide coalesced index/weight prefetch, edge loop
//    uses __shfl (no per-edge index load latency); GAT softmax via wave reduces
//  - GraphNorm column stats fused into agg kernels (128-slot atomic psum + tiny k_stats)
//  - multi-block scan replaces the single-block k_scan
//  - embed GEMM / lin GEMMs unchanged from r6 (embed is at its L2-miss floor)

typedef _Float16 f16;
typedef f16 f16x8 __attribute__((ext_vector_type(8)));
typedef f16 f16x4 __attribute__((ext_vector_type(4)));
typedef f16 f16x2 __attribute__((ext_vector_type(2)));
typedef float f32x4 __attribute__((ext_vector_type(4)));

__device__ __forceinline__ float lrelu(float x, float s){ return x>=0.f? x : s*x; }

// ---------------- CSR build ----------------
__global__ __launch_bounds__(256) void k_deg(const int* __restrict__ dst,
                                             int* __restrict__ deg, int E) {
  int i = blockIdx.x * 256 + threadIdx.x;
  if (i < E) atomicAdd(&deg[dst[i]], 1);
}

// pass 1: per-1024-chunk inclusive scan (+ dinv)
__global__ __launch_bounds__(1024) void k_scan1(const int* __restrict__ deg,
    int* __restrict__ row_ptr, int* __restrict__ bsum, float* __restrict__ dinv, int n) {
  int b = blockIdx.x, t = threadIdx.x, i = b * 1024 + t;
  __shared__ int sd[1024];
  int v = (i < n) ? deg[i] : 0;
  if (i < n) dinv[i] = rsqrtf((float)(v + 1));   // +1 self loop
  sd[t] = v;
  __syncthreads();
  for (int off = 1; off < 1024; off <<= 1) {
    int o = (t >= off) ? sd[t - off] : 0;
    __syncthreads();
    sd[t] += o;
    __syncthreads();
  }
  if (i < n) row_ptr[i + 1] = sd[t];
  if (t == 1023) bsum[b] = sd[1023];
  if (b == 0 && t == 0) row_ptr[0] = 0;
}

// pass 2: exclusive scan of block sums (nb <= 64)
__global__ __launch_bounds__(64) void k_scan2(int* __restrict__ bsum, int nb) {
  int lane = threadIdx.x;
  int v = (lane < nb) ? bsum[lane] : 0;
  int x = v;
  for (int off = 1; off < 64; off <<= 1) {
    int o = __shfl_up(x, off, 64);
    if (lane >= off) x += o;
  }
  if (lane < nb) bsum[lane] = x - v;
}

// pass 3: add chunk offsets
__global__ __launch_bounds__(256) void k_scan3(int* __restrict__ row_ptr,
                                               const int* __restrict__ bsum, int n) {
  int i = blockIdx.x * 256 + threadIdx.x;
  if (i < n) row_ptr[i + 1] += bsum[i >> 10];
}

// fill csr + per-edge gcn weight dinv[d]*dinv[s]
__global__ __launch_bounds__(256) void k_fill(const int* __restrict__ src,
                                              const int* __restrict__ dst,
                                              const int* __restrict__ row_ptr,
                                              const float* __restrict__ dinv,
                                              int* __restrict__ fill,
                                              int* __restrict__ csr,
                                              float* __restrict__ csrw, int E) {
  int i = blockIdx.x * 256 + threadIdx.x;
  if (i < E) {
    int d = dst[i], s = src[i];
    int pos = row_ptr[d] + atomicAdd(&fill[d], 1);
    csr[pos] = s;
    csrw[pos] = dinv[d] * dinv[s];
  }
}

// ---------------- conversions / packing ----------------
__global__ __launch_bounds__(256) void k_conv_emb(const float* __restrict__ src,
                                                  f16* __restrict__ dst, int total4) {
  int i = blockIdx.x * 256 + threadIdx.x;
  if (i >= total4) return;
  float4 v = ((const float4*)src)[i];
  f16x4 o = { (f16)v.x, (f16)v.y, (f16)v.z, (f16)v.w };
  ((f16x4*)dst)[i] = o;
}

__global__ __launch_bounds__(256) void k_pack_w(const float* __restrict__ W,
    f16* __restrict__ hi, int kb_total) {
  int idx = blockIdx.x * 256 + threadIdx.x;
  int c = idx & 127, kb = idx >> 7;
  if (kb >= kb_total) return;
  f16x8 hv;
#pragma unroll
  for (int j = 0; j < 8; j++) hv[j] = (f16)W[(size_t)(kb*8 + j) * 128 + c];
  ((f16x8*)hi)[idx] = hv;
}

__global__ __launch_bounds__(256) void k_pack_w8(const float* __restrict__ gcnW,
    const float* __restrict__ gatW, f16* __restrict__ hi, f16* __restrict__ lo) {
  int mat = blockIdx.y;
  const float* W = (mat < 4) ? gcnW + (size_t)mat * 16384 : gatW + (size_t)(mat - 4) * 16384;
  int idx = blockIdx.x * 256 + threadIdx.x;
  int c = idx & 127, kb = idx >> 7;
  f16x8 hv, lv;
#pragma unroll
  for (int j = 0; j < 8; j++) {
    float v = W[(size_t)(kb*8 + j) * 128 + c];
    f16 h = (f16)v;
    hv[j] = h; lv[j] = (f16)(v - (float)h);
  }
  ((f16x8*)hi)[mat * 2048 + idx] = hv;
  ((f16x8*)lo)[mat * 2048 + idx] = lv;
}

// ---------------- MFMA GEMM: embed-gather A, K=4128, dual K-half block ------------
#define APAD 152
__global__ __launch_bounds__(512) void k_mfma_embed(const int* __restrict__ poi,
    const float* __restrict__ dist, const f16* __restrict__ eh,
    const f16* __restrict__ wh, f16* __restrict__ H16, int n) {
  __shared__ __attribute__((aligned(16))) char smem[49152];
  int* poi_s = (int*)smem;
  f16* aS    = (f16*)(smem + 8192);
  f16* OT    = (f16*)smem;
  float* F   = (float*)(smem + 16384);
  int tid = threadIdx.x;
  int bn = blockIdx.x * 64;
  int half = tid >> 8;
  int t2 = tid & 255;
  int ln = t2 >> 2, qt = t2 & 3;
  int xrow = bn + ln; if (xrow > n - 1) xrow = n - 1;
  {
#pragma unroll
    for (int jj = 0; jj < 4; jj++)
      poi_s[half * 1024 + (qt * 4 + jj) * 64 + ln] =
        poi[(size_t)xrow * 32 + half * 16 + qt * 4 + jj];
  }
  int w2 = (tid >> 6) & 3, lane = tid & 63;
  int q = lane >> 4, l15 = lane & 15;
  int mtb = (w2 & 1) * 2;
  int ntb = (w2 >> 1) * 4;
  f16* aH = aS + half * 64 * APAD;
  f32x4 acc[2][4];
#pragma unroll
  for (int a = 0; a < 2; a++)
#pragma unroll
    for (int b = 0; b < 4; b++) { acc[a][b][0]=0.f; acc[a][b][1]=0.f; acc[a][b][2]=0.f; acc[a][b][3]=0.f; }
  __syncthreads();

  f16x8 r0, r1, r2, r3;
  {
    const f16* srcp = eh + (size_t)poi_s[half * 1024 + ln] * 128 + qt * 32;
    r0 = *(const f16x8*)(srcp);      r1 = *(const f16x8*)(srcp + 8);
    r2 = *(const f16x8*)(srcp + 16); r3 = *(const f16x8*)(srcp + 24);
  }

#pragma unroll 1
  for (int j = 0; j < 16; j++) {
    __syncthreads();
    f16* wp = aH + ln * APAD + qt * 32;
    *(f16x8*)(wp) = r0; *(f16x8*)(wp + 8) = r1;
    *(f16x8*)(wp + 16) = r2; *(f16x8*)(wp + 24) = r3;
    if (j + 1 < 16) {
      const f16* srcp = eh + (size_t)poi_s[half * 1024 + (j + 1) * 64 + ln] * 128 + qt * 32;
      r0 = *(const f16x8*)(srcp);      r1 = *(const f16x8*)(srcp + 8);
      r2 = *(const f16x8*)(srcp + 16); r3 = *(const f16x8*)(srcp + 24);
    }
    __syncthreads();
#pragma unroll
    for (int kcl = 0; kcl < 4; kcl++) {
      f16x8 a_h[2];
#pragma unroll
      for (int mi = 0; mi < 2; mi++)
        a_h[mi] = *(const f16x8*)(aH + ((mtb + mi) * 16 + l15) * APAD + kcl * 32 + q * 8);
      int kb = (half * 16 + j) * 16 + kcl * 4 + q;
#pragma unroll
      for (int ni = 0; ni < 4; ni++) {
        f16x8 bh = *(const f16x8*)(wh + ((size_t)kb * 128 + (ntb + ni) * 16 + l15) * 8);
#pragma unroll
        for (int mi = 0; mi < 2; mi++)
          acc[mi][ni] = __builtin_amdgcn_mfma_f32_16x16x32_f16(a_h[mi], bh, acc[mi][ni], 0, 0, 0);
      }
    }
  }
  if (half) {
    int nc0 = bn + (mtb + 0) * 16 + l15; if (nc0 > n - 1) nc0 = n - 1;
    int nc1 = bn + (mtb + 1) * 16 + l15; if (nc1 > n - 1) nc1 = n - 1;
    f16x8 ad[2];
#pragma unroll
    for (int mi = 0; mi < 2; mi++) {
      int nc = mi ? nc1 : nc0;
      const float* dp = dist + (size_t)nc * 32 + q * 8;
      float4 d0 = *(const float4*)dp, d1 = *(const float4*)(dp + 4);
      ad[mi][0]=(f16)d0.x; ad[mi][1]=(f16)d0.y; ad[mi][2]=(f16)d0.z; ad[mi][3]=(f16)d0.w;
      ad[mi][4]=(f16)d1.x; ad[mi][5]=(f16)d1.y; ad[mi][6]=(f16)d1.z; ad[mi][7]=(f16)d1.w;
    }
    int kb = 512 + q;
#pragma unroll
    for (int ni = 0; ni < 4; ni++) {
      f16x8 bh = *(const f16x8*)(wh + ((size_t)kb * 128 + (ntb + ni) * 16 + l15) * 8);
#pragma unroll
      for (int mi = 0; mi < 2; mi++)
        acc[mi][ni] = __builtin_amdgcn_mfma_f32_16x16x32_f16(ad[mi], bh, acc[mi][ni], 0, 0, 0);
    }
  }
  __syncthreads();
  if (half) {
#pragma unroll
    for (int mi = 0; mi < 2; mi++)
#pragma unroll
      for (int ni = 0; ni < 4; ni++)
#pragma unroll
        for (int r = 0; r < 4; r++)
          F[((mtb + mi) * 16 + q * 4 + r) * 128 + (ntb + ni) * 16 + l15] = acc[mi][ni][r];
  }
  __syncthreads();
  if (!half) {
#pragma unroll
    for (int mi = 0; mi < 2; mi++)
#pragma unroll
      for (int ni = 0; ni < 4; ni++)
#pragma unroll
        for (int r = 0; r < 4; r++) {
          int o = ((mtb + mi) * 16 + q * 4 + r) * 128 + (ntb + ni) * 16 + l15;
          OT[o] = (f16)(acc[mi][ni][r] + F[o]);
        }
  }
  __syncthreads();
#pragma unroll
  for (int ch = 0; ch < 2; ch++) {
    int c1024 = tid + ch * 512;
    int row = c1024 >> 4, c8 = c1024 & 15;
    if (bn + row < n)
      *(f16x8*)(H16 + (size_t)(bn + row) * 128 + c8 * 8) = *(const f16x8*)(OT + row * 128 + c8 * 8);
  }
}

// ---------------- MFMA GEMM: f16 A (xh), K=128; optional fused a-dot epilogue ----
#define LPAD 136
__global__ __launch_bounds__(256) void k_mfma_lin(const f16* __restrict__ XH,
    const f16* __restrict__ wh, const f16* __restrict__ wl,
    f16* __restrict__ H16, int n,
    const float* __restrict__ asrc, const float* __restrict__ adst,
    float* __restrict__ als, float* __restrict__ ald) {
  __shared__ __attribute__((aligned(16))) char smem[64 * LPAD * 2];
  f16* aS = (f16*)smem;
  f16* ot = (f16*)smem;
  float* dsrc = (float*)(smem + 16384);
  float* ddst = (float*)(smem + 16896);
  int tid = threadIdx.x;
  int bn = blockIdx.x * 64;
  int ln = tid >> 2, qt = tid & 3;
  int xrow = bn + ln; if (xrow > n - 1) xrow = n - 1;
  int w = tid >> 6, lane = tid & 63;
  int q = lane >> 4, l15 = lane & 15;
  int mtb = (w & 1) * 2;
  int ntb = (w >> 1) * 4;
  {
    const f16* srcp = XH + (size_t)xrow * 128 + qt * 32;
    f16* wp = aS + ln * LPAD + qt * 32;
    *(f16x8*)(wp)      = *(const f16x8*)(srcp);
    *(f16x8*)(wp + 8)  = *(const f16x8*)(srcp + 8);
    *(f16x8*)(wp + 16) = *(const f16x8*)(srcp + 16);
    *(f16x8*)(wp + 24) = *(const f16x8*)(srcp + 24);
  }
  float av[4], bv[4];
  if (asrc) {
#pragma unroll
    for (int ni = 0; ni < 4; ni++) {
      av[ni] = asrc[(ntb + ni) * 16 + l15];
      bv[ni] = adst[(ntb + ni) * 16 + l15];
    }
  }
  f32x4 acc[2][4];
#pragma unroll
  for (int a = 0; a < 2; a++)
#pragma unroll
    for (int b = 0; b < 4; b++) { acc[a][b][0]=0.f; acc[a][b][1]=0.f; acc[a][b][2]=0.f; acc[a][b][3]=0.f; }
  __syncthreads();
#pragma unroll
  for (int kcl = 0; kcl < 4; kcl++) {
    f16x8 a_h[2];
#pragma unroll
    for (int mi = 0; mi < 2; mi++)
      a_h[mi] = *(const f16x8*)(aS + ((mtb + mi) * 16 + l15) * LPAD + kcl * 32 + q * 8);
    int kb = kcl * 4 + q;
#pragma unroll
    for (int ni = 0; ni < 4; ni++) {
      size_t boff = ((size_t)kb * 128 + (ntb + ni) * 16 + l15) * 8;
      f16x8 bh = *(const f16x8*)(wh + boff);
      f16x8 bl = *(const f16x8*)(wl + boff);
#pragma unroll
      for (int mi = 0; mi < 2; mi++) {
        acc[mi][ni] = __builtin_amdgcn_mfma_f32_16x16x32_f16(a_h[mi], bh, acc[mi][ni], 0, 0, 0);
        acc[mi][ni] = __builtin_amdgcn_mfma_f32_16x16x32_f16(a_h[mi], bl, acc[mi][ni], 0, 0, 0);
      }
    }
  }
  __syncthreads();
  if (asrc) {
#pragma unroll
    for (int mi = 0; mi < 2; mi++)
#pragma unroll
      for (int r = 0; r < 4; r++) {
        float ps = 0.f, pd = 0.f;
#pragma unroll
        for (int ni = 0; ni < 4; ni++) { ps += acc[mi][ni][r] * av[ni]; pd += acc[mi][ni][r] * bv[ni]; }
#pragma unroll
        for (int msk = 8; msk > 0; msk >>= 1) {
          ps += __shfl_xor(ps, msk, 64);
          pd += __shfl_xor(pd, msk, 64);
        }
        if (l15 == 0) {
          int row = (mtb + mi) * 16 + q * 4 + r;
          dsrc[row * 2 + (w >> 1)] = ps;
          ddst[row * 2 + (w >> 1)] = pd;
        }
      }
  }
#pragma unroll
  for (int mi = 0; mi < 2; mi++)
#pragma unroll
    for (int ni = 0; ni < 4; ni++)
#pragma unroll
      for (int r = 0; r < 4; r++)
        ot[((mtb + mi) * 16 + q * 4 + r) * 128 + (ntb + ni) * 16 + l15] = (f16)acc[mi][ni][r];
  __syncthreads();
  if (bn + ln < n) {
    f16* dst = H16 + (size_t)(bn + ln) * 128 + qt * 32;
    const f16* srcp = ot + ln * 128 + qt * 32;
#pragma unroll
    for (int jj = 0; jj < 4; jj++)
      *(f16x8*)(dst + jj * 8) = *(const f16x8*)(srcp + jj * 8);
  }
  if (asrc && tid < 64 && bn + tid < n) {
    als[bn + tid] = dsrc[tid * 2] + dsrc[tid * 2 + 1];
    ald[bn + tid] = ddst[tid * 2] + ddst[tid * 2 + 1];
  }
}

// ---------------- GCN aggregation: staged-shuffle + fused column stats ----------
__global__ __launch_bounds__(256) void k_gcn_agg16(const f16x2* __restrict__ H2,
    const float* __restrict__ dinv, const int* __restrict__ row_ptr,
    const int* __restrict__ csr, const float* __restrict__ csrw,
    const float* __restrict__ bias,
    float2* __restrict__ out2, f16x2* __restrict__ xh_out, int n, int leaky_flag,
    float* __restrict__ psum, float* __restrict__ psumsq) {
  int w = threadIdx.x >> 6;
  int node = blockIdx.x * 4 + w;
  int lane = threadIdx.x & 63;
  __shared__ float s1[4][128], s2[4][128];
  float vx = 0.f, vy = 0.f;
  if (node < n) {
    int rs = row_ptr[node], re = row_ptr[node + 1];
    int d = re - rs;
    float dn = dinv[node];
    // stage indices & weights: one coalesced 64-wide load
    int  sidx = (lane < d) ? csr[rs + lane]  : 0;
    float swt = (lane < d) ? csrw[rs + lane] : 0.f;
    f16x2 sv = H2[(size_t)node * 64 + lane];
    float ax = dn * dn * (float)sv[0], ay = dn * dn * (float)sv[1];
    int dl = d < 64 ? d : 64;
    int j = 0;
#pragma unroll 4
    for (; j + 3 < dl; j += 4) {
      int i0 = __shfl(sidx, j, 64), i1 = __shfl(sidx, j + 1, 64);
      int i2 = __shfl(sidx, j + 2, 64), i3 = __shfl(sidx, j + 3, 64);
      float w0 = __shfl(swt, j, 64), w1 = __shfl(swt, j + 1, 64);
      float w2 = __shfl(swt, j + 2, 64), w3 = __shfl(swt, j + 3, 64);
      f16x2 v0 = H2[(size_t)i0 * 64 + lane];
      f16x2 v1 = H2[(size_t)i1 * 64 + lane];
      f16x2 v2 = H2[(size_t)i2 * 64 + lane];
      f16x2 v3 = H2[(size_t)i3 * 64 + lane];
      ax += w0*(float)v0[0] + w1*(float)v1[0] + w2*(float)v2[0] + w3*(float)v3[0];
      ay += w0*(float)v0[1] + w1*(float)v1[1] + w2*(float)v2[1] + w3*(float)v3[1];
    }
    for (; j < dl; j++) {
      int ii = __shfl(sidx, j, 64);
      float ww = __shfl(swt, j, 64);
      f16x2 v = H2[(size_t)ii * 64 + lane];
      ax += ww * (float)v[0]; ay += ww * (float)v[1];
    }
    for (int e = rs + 64; e < re; e++) {   // rare deg>64 tail
      int s = csr[e]; float wv = csrw[e];
      f16x2 v = H2[(size_t)s * 64 + lane];
      ax += wv * (float)v[0]; ay += wv * (float)v[1];
    }
    float2 bvv = ((const float2*)bias)[lane];
    vx = ax + bvv.x; vy = ay + bvv.y;
    if (leaky_flag) { vx = lrelu(vx, 0.01f); vy = lrelu(vy, 0.01f); }
    out2[(size_t)node * 64 + lane] = make_float2(vx, vy);
    if (xh_out) { f16x2 o = { (f16)vx, (f16)vy }; xh_out[(size_t)node * 64 + lane] = o; }
  }
  if (psum) {
    s1[w][2*lane] = vx;  s1[w][2*lane+1] = vy;
    s2[w][2*lane] = vx*vx; s2[w][2*lane+1] = vy*vy;
    __syncthreads();
    int t = threadIdx.x;
    if (t < 128) {
      float S = s1[0][t] + s1[1][t] + s1[2][t] + s1[3][t];
      float Q = s2[0][t] + s2[1][t] + s2[2][t] + s2[3][t];
      int slot = blockIdx.x & 127;
      atomicAdd(&psum[slot * 128 + t], S);
      atomicAdd(&psumsq[slot * 128 + t], Q);
    }
  }
}

// ---------------- GAT aggregation: staged-shuffle softmax + fused stats ---------
__global__ __launch_bounds__(256) void k_gat_agg16(const f16x2* __restrict__ H2,
    const float* __restrict__ als, const float* __restrict__ ald,
    const int* __restrict__ row_ptr, const int* __restrict__ csr,
    const float* __restrict__ bias, float2* __restrict__ y2, int n,
    float* __restrict__ psum, float* __restrict__ psumsq) {
  int w = threadIdx.x >> 6;
  int node = blockIdx.x * 4 + w;
  int lane = threadIdx.x & 63;
  __shared__ float s1[4][128], s2[4][128];
  float vx = 0.f, vy = 0.f;
  if (node < n) {
    int rs = row_ptr[node], re = row_ptr[node + 1];
    int d = re - rs;
    float aldn = ald[node];
    float e_self = lrelu(als[node] + aldn, 0.2f);
    f16x2 sv = H2[(size_t)node * 64 + lane];
    float ax, ay, sm;
    if (d <= 64) {
      int sidx = (lane < d) ? csr[rs + lane] : 0;
      float e_k = (lane < d) ? lrelu(als[sidx] + aldn, 0.2f) : -3.4e38f;
      float tmx = e_k;
      for (int off = 1; off < 64; off <<= 1) tmx = fmaxf(tmx, __shfl_xor(tmx, off, 64));
      float mx = fmaxf(e_self, tmx);
      float g_k = (lane < d) ? __expf(e_k - mx) : 0.f;
      float tsm = g_k;
      for (int off = 1; off < 64; off <<= 1) tsm += __shfl_xor(tsm, off, 64);
      float ws = __expf(e_self - mx);
      sm = tsm + ws;
      ax = ws * (float)sv[0]; ay = ws * (float)sv[1];
      int j = 0;
#pragma unroll 4
      for (; j + 3 < d; j += 4) {
        int i0 = __shfl(sidx, j, 64), i1 = __shfl(sidx, j + 1, 64);
        int i2 = __shfl(sidx, j + 2, 64), i3 = __shfl(sidx, j + 3, 64);
        float g0 = __shfl(g_k, j, 64), g1 = __shfl(g_k, j + 1, 64);
        float g2 = __shfl(g_k, j + 2, 64), g3 = __shfl(g_k, j + 3, 64);
        f16x2 v0 = H2[(size_t)i0 * 64 + lane];
        f16x2 v1 = H2[(size_t)i1 * 64 + lane];
        f16x2 v2 = H2[(size_t)i2 * 64 + lane];
        f16x2 v3 = H2[(size_t)i3 * 64 + lane];
        ax += g0*(float)v0[0] + g1*(float)v1[0] + g2*(float)v2[0] + g3*(float)v3[0];
        ay += g0*(float)v0[1] + g1*(float)v1[1] + g2*(float)v2[1] + g3*(float)v3[1];
      }
      for (; j < d; j++) {
        int ii = __shfl(sidx, j, 64);
        float gg = __shfl(g_k, j, 64);
        f16x2 v = H2[(size_t)ii * 64 + lane];
        ax += gg * (float)v[0]; ay += gg * (float)v[1];
      }
    } else {  // rare deg>64 slow path
      float mx = e_self;
      for (int i = rs + lane; i < re; i += 64) mx = fmaxf(mx, lrelu(als[csr[i]] + aldn, 0.2f));
      for (int off = 1; off < 64; off <<= 1) mx = fmaxf(mx, __shfl_xor(mx, off, 64));
      float ws = __expf(e_self - mx);
      sm = ws;
      ax = ws * (float)sv[0]; ay = ws * (float)sv[1];
      for (int i = rs; i < re; i++) {
        int s = csr[i];
        float g = __expf(lrelu(als[s] + aldn, 0.2f) - mx);
        f16x2 v = H2[(size_t)s * 64 + lane];
        sm += g; ax += g*(float)v[0]; ay += g*(float)v[1];
      }
    }
    float inv_s = 1.f / sm;
    float2 bvv = ((const float2*)bias)[lane];
    vx = ax * inv_s + bvv.x; vy = ay * inv_s + bvv.y;
    y2[(size_t)node * 64 + lane] = make_float2(vx, vy);
  }
  s1[w][2*lane] = vx;  s1[w][2*lane+1] = vy;
  s2[w][2*lane] = vx*vx; s2[w][2*lane+1] = vy*vy;
  __syncthreads();
  int t = threadIdx.x;
  if (t < 128) {
    float S = s1[0][t] + s1[1][t] + s1[2][t] + s1[3][t];
    float Q = s2[0][t] + s2[1][t] + s2[2][t] + s2[3][t];
    int slot = blockIdx.x & 127;
    atomicAdd(&psum[slot * 128 + t], S);
    atomicAdd(&psumsq[slot * 128 + t], Q);
  }
}

// ---------------- GraphNorm stats (reads 128-slot partials) ----------------
__global__ __launch_bounds__(256) void k_stats(const float* __restrict__ psum,
    const float* __restrict__ psumsq, const float* __restrict__ w,
    const float* __restrict__ bb, const float* __restrict__ ms,
    float* __restrict__ scaleA, float* __restrict__ shiftA, int n) {
  int t = threadIdx.x, c = t & 127, half = t >> 7;
  float S = 0.f, Q = 0.f;
  for (int s = half; s < 128; s += 2) { S += psum[s * 128 + c]; Q += psumsq[s * 128 + c]; }
  __shared__ float sh[256], sq[256];
  sh[t] = S; sq[t] = Q;
  __syncthreads();
  if (half == 0) {
    double Sd = (double)sh[c] + (double)sh[c + 128];
    double Qd = (double)sq[c] + (double)sq[c + 128];
    double invn = 1.0 / (double)n;
    double mean = Sd * invn;
    double mt = (double)ms[c] * mean;
    double var = Qd * invn - 2.0 * mt * mean + mt * mt;
    float rstd = rsqrtf((float)var + 1e-5f);
    float sc = w[c] * rstd;
    scaleA[c] = sc;
    shiftA[c] = bb[c] - sc * (float)mt;
  }
}

// ---------------- residual (+ xh f16 emit) ----------------
__global__ __launch_bounds__(256) void k_residual(const float* __restrict__ y,
    const float* __restrict__ scaleA, const float* __restrict__ shiftA,
    float* __restrict__ x, f16x4* __restrict__ xh, int n4) {
  int i = blockIdx.x * 256 + threadIdx.x;
  if (i >= n4) return;
  int c4 = (i & 31) * 4;
  float4 yv = ((const float4*)y)[i];
  float4 xv = ((float4*)x)[i];
  float4 sc = *(const float4*)(scaleA + c4);
  float4 sh = *(const float4*)(shiftA + c4);
  xv.x += lrelu(sc.x * yv.x + sh.x, 0.01f);
  xv.y += lrelu(sc.y * yv.y + sh.y, 0.01f);
  xv.z += lrelu(sc.z * yv.z + sh.z, 0.01f);
  xv.w += lrelu(sc.w * yv.w + sh.w, 0.01f);
  ((float4*)x)[i] = xv;
  if (xh) { f16x4 o = { (f16)xv.x, (f16)xv.y, (f16)xv.z, (f16)xv.w }; xh[i] = o; }
}

// ---------------- Output head ----------------
__global__ __launch_bounds__(256) void k_dot1(const float* __restrict__ x,
                                              const float* __restrict__ wv,
                                              float* __restrict__ o, int n) {
  int node = blockIdx.x * 4 + (threadIdx.x >> 6);
  int lane = threadIdx.x & 63;
  if (node >= n) return;
  float2 hv = ((const float2*)x)[(size_t)node * 64 + lane];
  float2 v1 = ((const float2*)wv)[lane];
  float s1 = hv.x * v1.x + hv.y * v1.y;
  for (int off = 32; off > 0; off >>= 1) s1 += __shfl_down(s1, off, 64);
  if (lane == 0) o[node] = s1;
}

__global__ __launch_bounds__(256) void k_scalar_agg(const float* __restrict__ xsv,
    const float* __restrict__ dinv, const int* __restrict__ row_ptr,
    const int* __restrict__ csr, const float* __restrict__ csrw,
    const float* __restrict__ b_out, float* __restrict__ xout, int n) {
  int i = blockIdx.x * 256 + threadIdx.x;
  if (i >= n) return;
  float dn = dinv[i];
  float acc = dn * dn * xsv[i];
  int re = row_ptr[i + 1];
  for (int e = row_ptr[i]; e < re; e++)
    acc += csrw[e] * xsv[csr[e]];
  xout[i] = lrelu(acc + b_out[0], 0.01f);
}

__global__ __launch_bounds__(256) void k_fc1(const float* __restrict__ xout,
    const float* __restrict__ fw, float* __restrict__ pfc, int n, int chunk) {
  int b = blockIdx.x, t = threadIdx.x;
  int c = t & 127, half = t >> 7;
  int s0 = b * chunk;
  int s1 = s0 + chunk; if (s1 > n) s1 = n;
  float s = 0.f;
  for (int i = s0 + half; i < s1; i += 2) s += xout[i] * fw[(size_t)i * 128 + c];
  __shared__ float sh[256];
  sh[t] = s; __syncthreads();
  if (half == 0) pfc[b * 128 + c] = sh[c] + sh[c + 128];
}

__global__ __launch_bounds__(128) void k_final(const float* __restrict__ pfc,
    const float* __restrict__ b1, const float* __restrict__ fw2,
    const float* __restrict__ b2, float* __restrict__ out) {
  int c = threadIdx.x;
  float s = 0.f;
  for (int b = 0; b < 128; b++) s += pfc[b * 128 + c];
  float hv = lrelu(s + b1[c], 0.01f);
  __shared__ float h1[128];
  h1[c] = hv; __syncthreads();
  float o = b2[c];
  for (int j = 0; j < 128; j++) o += h1[j] * fw2[j * 128 + c];
  out[c] = o;
}

// ---------------- host ----------------
extern "C" void kernel_launch(void* const* d_in, const int* in_sizes, int n_in,
                              void* d_out, int out_size, void* d_ws, size_t ws_size,
                              hipStream_t stream) {
  const int* poi      = (const int*)d_in[0];
  const float* dist   = (const float*)d_in[1];
  const int* ei       = (const int*)d_in[2];
  const float* emb    = (const float*)d_in[3];
  const float* W_in   = (const float*)d_in[4];
  const float* b_in   = (const float*)d_in[5];
  const float* gcn_W  = (const float*)d_in[6];
  const float* gcn_b  = (const float*)d_in[7];
  const float* norm_w = (const float*)d_in[8];
  const float* norm_b = (const float*)d_in[9];
  const float* norm_ms= (const float*)d_in[10];
  const float* gat_W  = (const float*)d_in[11];
  const float* gat_as = (const float*)d_in[12];
  const float* gat_ad = (const float*)d_in[13];
  const float* gat_b  = (const float*)d_in[14];
  const float* W_out  = (const float*)d_in[15];
  const float* b_out  = (const float*)d_in[16];
  const float* fc1_W  = (const float*)d_in[17];
  const float* fc1_b  = (const float*)d_in[18];
  const float* fc2_W  = (const float*)d_in[19];
  const float* fc2_b  = (const float*)d_in[20];

  const int N   = in_sizes[0] / 32;
  const int E   = in_sizes[2] / 2;
  const int POI = in_sizes[3] / 128;
  const int* srcp = ei;
  const int* dstp = ei + E;
  float* out = (float*)d_out;

  char* p = (char*)d_ws;
  auto alloc = [&](size_t bytes) { char* r = p; p += (bytes + 255) & ~(size_t)255; return r; };
  float* x   = (float*)alloc((size_t)N * 128 * 4);
  f16* h16   = (f16*)alloc((size_t)N * 128 * 2);
  f16* xh    = (f16*)alloc((size_t)N * 128 * 2);
  size_t Rneed = (size_t)POI * 128 * 2;
  size_t Ry    = (size_t)N * 128 * 4;
  char* R = alloc(Rneed > Ry ? Rneed : Ry);
  f16* ehalf = (f16*)R;
  float* y   = (float*)R;
  const int KBIN = 4128 / 8;
  f16* wih = (f16*)alloc((size_t)KBIN * 128 * 8 * 2);
  f16* wsh = (f16*)alloc((size_t)8 * 16384 * 2);
  f16* wsl = (f16*)alloc((size_t)8 * 16384 * 2);
  float* dinv   = (float*)alloc((size_t)N * 4);
  float* als    = (float*)alloc((size_t)N * 4);
  float* ald    = (float*)alloc((size_t)N * 4);
  float* xsv    = (float*)alloc((size_t)N * 4);
  float* xout   = (float*)alloc((size_t)N * 4);
  // 16 layer-stage psum/psumsq pairs (128 slots x 128 ch), zeroed once per launch
  float* statsbuf = (float*)alloc((size_t)32 * 16384 * 4);   // 2 MB
  float* pfc    = (float*)alloc(128 * 128 * 4);
  float* scaleA = (float*)alloc(128 * 4);
  float* shiftA = (float*)alloc(128 * 4);
  int* deg     = (int*)alloc((size_t)N * 2 * 4);   // deg+fill contiguous: one memset
  int* fill    = deg + N;
  int* row_ptr = (int*)alloc(((size_t)N + 1) * 4);
  int* csr     = (int*)alloc((size_t)E * 4);
  float* csrw  = (float*)alloc((size_t)E * 4);
  int* bsum    = (int*)alloc(64 * 4);

  const int chunk = (N + 127) / 128;
  const int gblocks = (N + 63) / 64;
  const int eblocks = (E + 255) / 256;
  const int n4 = N * 32;
  const int nwb = (N + 3) / 4;
  const int nb1024 = (N + 1023) / 1024;

  hipMemsetAsync(deg, 0, sizeof(int) * 2 * (size_t)N, stream);
  hipMemsetAsync(statsbuf, 0, (size_t)32 * 16384 * 4, stream);
  k_deg<<<eblocks, 256, 0, stream>>>(dstp, deg, E);
  k_scan1<<<nb1024, 1024, 0, stream>>>(deg, row_ptr, bsum, dinv, N);
  k_scan2<<<1, 64, 0, stream>>>(bsum, nb1024);
  k_scan3<<<(N + 255) / 256, 256, 0, stream>>>(row_ptr, bsum, N);
  k_fill<<<eblocks, 256, 0, stream>>>(srcp, dstp, row_ptr, dinv, fill, csr, csrw, E);

  int et4 = POI * 128 / 4;
  k_conv_emb<<<(et4 + 255) / 256, 256, 0, stream>>>(emb, ehalf, et4);
  k_pack_w<<<(KBIN * 128 + 255) / 256, 256, 0, stream>>>(W_in, wih, KBIN);
  k_pack_w8<<<dim3(8, 8), 256, 0, stream>>>(gcn_W, gat_W, wsh, wsl);

  // input layer
  k_mfma_embed<<<gblocks, 512, 0, stream>>>(poi, dist, ehalf, wih, h16, N);
  k_gcn_agg16<<<nwb, 256, 0, stream>>>((const f16x2*)h16, dinv, row_ptr, csr, csrw, b_in,
                                       (float2*)x, (f16x2*)xh, N, 1, nullptr, nullptr);

  for (int l = 0; l < 4; l++) {
    const f16* gh = wsh + (size_t)l * 16384;
    const f16* gl = wsl + (size_t)l * 16384;
    const f16* th = wsh + (size_t)(4 + l) * 16384;
    const f16* tl = wsl + (size_t)(4 + l) * 16384;
    float* ps0 = statsbuf + (size_t)(4 * l) * 16384;       // gcn psum
    float* pq0 = ps0 + 16384;                              // gcn psumsq
    float* ps1 = ps0 + 2 * 16384;                          // gat psum
    float* pq1 = ps0 + 3 * 16384;                          // gat psumsq
    // GCN sub-unit
    k_mfma_lin<<<gblocks, 256, 0, stream>>>(xh, gh, gl, h16, N,
                                            (const float*)nullptr, (const float*)nullptr,
                                            (float*)nullptr, (float*)nullptr);
    k_gcn_agg16<<<nwb, 256, 0, stream>>>((const f16x2*)h16, dinv, row_ptr, csr, csrw,
                                         gcn_b + l * 128, (float2*)y, (f16x2*)nullptr, N, 0,
                                         ps0, pq0);
    k_stats<<<1, 256, 0, stream>>>(ps0, pq0, norm_w + l * 128, norm_b + l * 128,
                                   norm_ms + l * 128, scaleA, shiftA, N);
    k_residual<<<(n4 + 255) / 256, 256, 0, stream>>>(y, scaleA, shiftA, x, (f16x4*)xh, n4);
    // GAT sub-unit (dot2 fused into lin epilogue)
    k_mfma_lin<<<gblocks, 256, 0, stream>>>(xh, th, tl, h16, N,
                                            gat_as + l * 128, gat_ad + l * 128, als, ald);
    k_gat_agg16<<<nwb, 256, 0, stream>>>((const f16x2*)h16, als, ald, row_ptr, csr,
                                         gat_b + l * 128, (float2*)y, N, ps1, pq1);
    k_stats<<<1, 256, 0, stream>>>(ps1, pq1, norm_w + l * 128, norm_b + l * 128,
                                   norm_ms + l * 128, scaleA, shiftA, N);
    k_residual<<<(n4 + 255) / 256, 256, 0, stream>>>(y, scaleA, shiftA, x,
        (l == 3) ? (f16x4*)nullptr : (f16x4*)xh, n4);
  }

  // output head
  k_dot1<<<nwb, 256, 0, stream>>>(x, W_out, xsv, N);
  k_scalar_agg<<<(N + 255) / 256, 256, 0, stream>>>(xsv, dinv, row_ptr, csr, csrw, b_out, xout, N);
  k_fc1<<<128, 256, 0, stream>>>(xout, fc1_W, pfc, N, chunk);
  k_final<<<1, 128, 0, stream>>>(pfc, fc1_b, fc2_W, fc2_b, out);
}